// Round 2
// baseline (11764.164 us; speedup 1.0000x reference)
//
#include <hip/hip_runtime.h>

#define HID 128
#define NN  100000
#define EE  1600000
#define BB  512
#define LL  4

// ---------------------------------------------------------------------------
// x[i] = node_emb[x_idx[i]]  (N x 128, float4-vectorized, 32 threads/node)
// ---------------------------------------------------------------------------
__global__ __launch_bounds__(256) void embed_kernel(
    const int* __restrict__ x_idx, const float* __restrict__ node_emb,
    float* __restrict__ x)
{
    int t = blockIdx.x * 256 + threadIdx.x;     // t in [0, N*32)
    int node = t >> 5, j = t & 31;
    if (node >= NN) return;
    ((float4*)x)[node * 32 + j] =
        ((const float4*)node_emb)[x_idx[node] * 32 + j];
}

// ---------------------------------------------------------------------------
// per edge e: msg = relu(x[src] + e1[a0] + e2[a1] + e3[a2]); agg[dst] += msg
// 32 threads per edge, float4 per thread, atomicAdd scatter.
// e1/e2/e3 are 21x128 each (~10.5 KB) -> L1/L2 resident, read directly.
// ---------------------------------------------------------------------------
__global__ __launch_bounds__(256) void edge_kernel(
    const float* __restrict__ x, const int* __restrict__ ei,
    const int* __restrict__ ea, const float* __restrict__ e1,
    const float* __restrict__ e2, const float* __restrict__ e3,
    float* __restrict__ agg)
{
    int t = blockIdx.x * 256 + threadIdx.x;     // t in [0, E*32)
    int e = t >> 5, j = t & 31;
    if (e >= EE) return;
    int src = ei[e];
    int dst = ei[EE + e];
    int a0 = ea[e * 3 + 0], a1 = ea[e * 3 + 1], a2 = ea[e * 3 + 2];

    float4 v  = ((const float4*)x )[src * 32 + j];
    float4 w1 = ((const float4*)e1)[a0  * 32 + j];
    float4 w2 = ((const float4*)e2)[a1  * 32 + j];
    float4 w3 = ((const float4*)e3)[a2  * 32 + j];

    float mx = fmaxf(v.x + w1.x + w2.x + w3.x, 0.f);
    float my = fmaxf(v.y + w1.y + w2.y + w3.y, 0.f);
    float mz = fmaxf(v.z + w1.z + w2.z + w3.z, 0.f);
    float mw = fmaxf(v.w + w1.w + w2.w + w3.w, 0.f);

    float* ag = agg + (size_t)dst * HID + j * 4;
    atomicAdd(ag + 0, mx);
    atomicAdd(ag + 1, my);
    atomicAdd(ag + 2, mz);
    atomicAdd(ag + 3, mw);
}

// ---------------------------------------------------------------------------
// t = relu((x + agg) @ W + b)    [N,128]x[128,128]
// Block: 256 threads, tile 32 rows x 128 cols, 4x4 micro-tile per thread.
// h tile staged in LDS (pad 129 -> conflict-free); W streamed from L2.
// Safe to alias t == agg (block reads only its own rows before writing them).
// ---------------------------------------------------------------------------
__global__ __launch_bounds__(256) void gemm_relu_kernel(
    const float* __restrict__ x, const float* __restrict__ agg,
    const float* __restrict__ W, const float* __restrict__ bias,
    float* __restrict__ t)
{
    __shared__ float h_s[32 * 129];
    int tid = threadIdx.x;
    int tc = tid & 31;          // column group: cols 4*tc .. 4*tc+3
    int tr = tid >> 5;          // row group:    rows 4*tr .. 4*tr+3
    int rbase = blockIdx.x * 32;

    for (int idx = tid; idx < 32 * 128; idx += 256) {
        int r = idx >> 7, k = idx & 127;
        int g = (rbase + r) * HID + k;
        h_s[r * 129 + k] = x[g] + agg[g];
    }
    __syncthreads();

    float acc[4][4] = {};
    const float4* W4 = (const float4*)W;
#pragma unroll 4
    for (int k = 0; k < 128; ++k) {
        float4 w = W4[k * 32 + tc];
#pragma unroll
        for (int j = 0; j < 4; ++j) {
            float hv = h_s[(tr * 4 + j) * 129 + k];
            acc[j][0] = fmaf(hv, w.x, acc[j][0]);
            acc[j][1] = fmaf(hv, w.y, acc[j][1]);
            acc[j][2] = fmaf(hv, w.z, acc[j][2]);
            acc[j][3] = fmaf(hv, w.w, acc[j][3]);
        }
    }
    float4 bv = ((const float4*)bias)[tc];
#pragma unroll
    for (int j = 0; j < 4; ++j) {
        int r = rbase + tr * 4 + j;
        float4 o;
        o.x = fmaxf(acc[j][0] + bv.x, 0.f);
        o.y = fmaxf(acc[j][1] + bv.y, 0.f);
        o.z = fmaxf(acc[j][2] + bv.z, 0.f);
        o.w = fmaxf(acc[j][3] + bv.w, 0.f);
        ((float4*)t)[r * 32 + tc] = o;
    }
}

// ---------------------------------------------------------------------------
// u = t @ W + b;  x += relu(layer_norm(u, g, bt))
// Same tiling; per-row LN via half-wave (32-lane) shfl_xor reduction.
// ---------------------------------------------------------------------------
__global__ __launch_bounds__(256) void gemm_ln_res_kernel(
    const float* __restrict__ t, const float* __restrict__ W,
    const float* __restrict__ bias, const float* __restrict__ gamma,
    const float* __restrict__ beta, float* __restrict__ x)
{
    __shared__ float h_s[32 * 129];
    int tid = threadIdx.x;
    int tc = tid & 31;
    int tr = tid >> 5;
    int rbase = blockIdx.x * 32;

    for (int idx = tid; idx < 32 * 128; idx += 256) {
        int r = idx >> 7, k = idx & 127;
        h_s[r * 129 + k] = t[(rbase + r) * HID + k];
    }
    __syncthreads();

    float acc[4][4] = {};
    const float4* W4 = (const float4*)W;
#pragma unroll 4
    for (int k = 0; k < 128; ++k) {
        float4 w = W4[k * 32 + tc];
#pragma unroll
        for (int j = 0; j < 4; ++j) {
            float hv = h_s[(tr * 4 + j) * 129 + k];
            acc[j][0] = fmaf(hv, w.x, acc[j][0]);
            acc[j][1] = fmaf(hv, w.y, acc[j][1]);
            acc[j][2] = fmaf(hv, w.z, acc[j][2]);
            acc[j][3] = fmaf(hv, w.w, acc[j][3]);
        }
    }
    float4 bv = ((const float4*)bias)[tc];
    float4 gv = ((const float4*)gamma)[tc];
    float4 btv = ((const float4*)beta)[tc];
#pragma unroll
    for (int j = 0; j < 4; ++j) {
        acc[j][0] += bv.x; acc[j][1] += bv.y;
        acc[j][2] += bv.z; acc[j][3] += bv.w;
        float s = acc[j][0] + acc[j][1] + acc[j][2] + acc[j][3];
        float q = acc[j][0]*acc[j][0] + acc[j][1]*acc[j][1]
                + acc[j][2]*acc[j][2] + acc[j][3]*acc[j][3];
        // reduce across the 32 lanes (same tr) within each half-wave
#pragma unroll
        for (int off = 1; off < 32; off <<= 1) {
            s += __shfl_xor(s, off, 64);
            q += __shfl_xor(q, off, 64);
        }
        float m  = s * (1.f / 128.f);
        float var = q * (1.f / 128.f) - m * m;
        float rs = rsqrtf(var + 1e-5f);

        int r = rbase + tr * 4 + j;
        float4 xo = ((float4*)x)[r * 32 + tc];
        float4 o;
        o.x = xo.x + fmaxf((acc[j][0] - m) * rs * gv.x + btv.x, 0.f);
        o.y = xo.y + fmaxf((acc[j][1] - m) * rs * gv.y + btv.y, 0.f);
        o.z = xo.z + fmaxf((acc[j][2] - m) * rs * gv.z + btv.z, 0.f);
        o.w = xo.w + fmaxf((acc[j][3] - m) * rs * gv.w + btv.w, 0.f);
        ((float4*)x)[r * 32 + tc] = o;
    }
}

// ---------------------------------------------------------------------------
// mean-pool scatter: sums[batch[n]] += x[n]; cnt[batch[n]] += 1
// ---------------------------------------------------------------------------
__global__ __launch_bounds__(256) void pool_kernel(
    const float* __restrict__ x, const int* __restrict__ batch,
    float* __restrict__ sums, int* __restrict__ cnt)
{
    int t = blockIdx.x * 256 + threadIdx.x;
    int node = t >> 5, j = t & 31;
    if (node >= NN) return;
    int b = batch[node];
    float4 v = ((const float4*)x)[node * 32 + j];
    float* sp = sums + b * HID + j * 4;
    atomicAdd(sp + 0, v.x);
    atomicAdd(sp + 1, v.y);
    atomicAdd(sp + 2, v.z);
    atomicAdd(sp + 3, v.w);
    if (j == 0) atomicAdd(&cnt[b], 1);
}

// ---------------------------------------------------------------------------
// head: g = sums/cnt; h1=relu(g@pW1+pb1); h2=h1@pW2+pb2;
//       v=relu(LN(h2)); out=sigmoid(v@oW+ob).  One block (128 thr) per graph.
// ---------------------------------------------------------------------------
__global__ __launch_bounds__(128) void head_kernel(
    const float* __restrict__ sums, const int* __restrict__ cnt,
    const float* __restrict__ pW1, const float* __restrict__ pb1,
    const float* __restrict__ pW2, const float* __restrict__ pb2,
    const float* __restrict__ pg, const float* __restrict__ pbn,
    const float* __restrict__ oW, const float* __restrict__ ob,
    float* __restrict__ out)
{
    __shared__ float s0[128], s1[128], red[4];
    int b = blockIdx.x, c = threadIdx.x;

    float cn = fmaxf((float)cnt[b], 1.f);
    s0[c] = sums[b * HID + c] / cn;
    __syncthreads();

    float a = pb1[c];
#pragma unroll 4
    for (int k = 0; k < HID; ++k) a = fmaf(s0[k], pW1[k * HID + c], a);
    a = fmaxf(a, 0.f);
    s1[c] = a;
    __syncthreads();

    float u = pb2[c];
#pragma unroll 4
    for (int k = 0; k < HID; ++k) u = fmaf(s1[k], pW2[k * HID + c], u);

    float s = u, q = u * u;
#pragma unroll
    for (int off = 1; off < 64; off <<= 1) {
        s += __shfl_xor(s, off, 64);
        q += __shfl_xor(q, off, 64);
    }
    if ((c & 63) == 0) { red[(c >> 6) * 2] = s; red[(c >> 6) * 2 + 1] = q; }
    __syncthreads();
    float S = red[0] + red[2], Q = red[1] + red[3];
    float m = S * (1.f / 128.f);
    float var = Q * (1.f / 128.f) - m * m;
    float rs = rsqrtf(var + 1e-5f);
    float v = fmaxf((u - m) * rs * pg[c] + pbn[c], 0.f);

    float p = v * oW[c];                 // oW is [128,1]
#pragma unroll
    for (int off = 1; off < 64; off <<= 1) p += __shfl_xor(p, off, 64);
    __syncthreads();                     // red[] reused below
    if ((c & 63) == 0) red[c >> 6] = p;
    __syncthreads();
    if (c == 0) {
        float tot = red[0] + red[1] + ob[0];
        out[b] = 1.f / (1.f + expf(-tot));
    }
}

// ---------------------------------------------------------------------------
extern "C" void kernel_launch(void* const* d_in, const int* in_sizes, int n_in,
                              void* d_out, int out_size, void* d_ws, size_t ws_size,
                              hipStream_t stream)
{
    const int*   x_idx    = (const int*)d_in[0];
    const int*   ei       = (const int*)d_in[1];
    const int*   ea       = (const int*)d_in[2];
    const int*   batch    = (const int*)d_in[3];
    const float* node_emb = (const float*)d_in[4];
    const float* e1       = (const float*)d_in[5];
    const float* e2       = (const float*)d_in[6];
    const float* e3       = (const float*)d_in[7];
    const float* W1       = (const float*)d_in[8];
    const float* b1       = (const float*)d_in[9];
    const float* W2       = (const float*)d_in[10];
    const float* b2       = (const float*)d_in[11];
    const float* lg       = (const float*)d_in[12];
    const float* lb       = (const float*)d_in[13];
    const float* pW1      = (const float*)d_in[14];
    const float* pb1      = (const float*)d_in[15];
    const float* pW2      = (const float*)d_in[16];
    const float* pb2      = (const float*)d_in[17];
    const float* pg       = (const float*)d_in[18];
    const float* pbn      = (const float*)d_in[19];
    const float* oW       = (const float*)d_in[20];
    const float* ob       = (const float*)d_in[21];
    float* out = (float*)d_out;

    float* x    = (float*)d_ws;                       // N*128 f32 (51.2 MB)
    float* agg  = x + (size_t)NN * HID;               // N*128 f32, doubles as t
    float* sums = agg + (size_t)NN * HID;             // B*128 f32
    int*   cnt  = (int*)(sums + (size_t)BB * HID);    // B int

    embed_kernel<<<(NN * 32 + 255) / 256, 256, 0, stream>>>(x_idx, node_emb, x);

    for (int l = 0; l < LL; ++l) {
        hipMemsetAsync(agg, 0, (size_t)NN * HID * sizeof(float), stream);
        edge_kernel<<<(EE * 32 + 255) / 256, 256, 0, stream>>>(
            x, ei, ea, e1, e2, e3, agg);
        gemm_relu_kernel<<<NN / 32, 256, 0, stream>>>(
            x, agg, W1 + l * HID * HID, b1 + l * HID, agg /* t aliases agg */);
        gemm_ln_res_kernel<<<NN / 32, 256, 0, stream>>>(
            agg, W2 + l * HID * HID, b2 + l * HID,
            lg + l * HID, lb + l * HID, x);
    }

    hipMemsetAsync(sums, 0,
                   (size_t)BB * HID * sizeof(float) + BB * sizeof(int), stream);
    pool_kernel<<<(NN * 32 + 255) / 256, 256, 0, stream>>>(x, batch, sums, cnt);
    head_kernel<<<BB, 128, 0, stream>>>(
        sums, cnt, pW1, pb1, pW2, pb2, pg, pbn, oW, ob, out);
}

// Round 3
// 2325.578 us; speedup vs baseline: 5.0586x; 5.0586x over previous
//
#include <hip/hip_runtime.h>

#define HID 128
#define NN  100000
#define EE  1600000
#define BB  512
#define LL  4

// ============================ CSR build ====================================
// R has NN+1 ints. Phase 1: R[dst+1]++ (histogram, offset by one).
__global__ __launch_bounds__(256) void hist_kernel(
    const int* __restrict__ ei, int* __restrict__ R)
{
    int e = blockIdx.x * 256 + threadIdx.x;
    if (e >= EE) return;
    atomicAdd(&R[ei[EE + e] + 1], 1);
}

// Phase 2: inclusive prefix scan of R[0..n) (3-kernel scan, 1024 elems/block)
__global__ __launch_bounds__(256) void scan1_kernel(int* __restrict__ R,
                                                    int* __restrict__ aux, int n)
{
    __shared__ int sh[256];
    int base = blockIdx.x * 1024;
    int t = threadIdx.x;
    int v[4]; int s = 0;
#pragma unroll
    for (int i = 0; i < 4; ++i) {
        int idx = base + t * 4 + i;
        v[i] = (idx < n) ? R[idx] : 0;
        s += v[i];
    }
    sh[t] = s; __syncthreads();
#pragma unroll
    for (int off = 1; off < 256; off <<= 1) {
        int val = (t >= off) ? sh[t - off] : 0;
        __syncthreads();
        sh[t] += val;
        __syncthreads();
    }
    int run = (t == 0) ? 0 : sh[t - 1];
#pragma unroll
    for (int i = 0; i < 4; ++i) {
        int idx = base + t * 4 + i;
        run += v[i];
        if (idx < n) R[idx] = run;
    }
    if (t == 255) aux[blockIdx.x] = sh[255];
}

__global__ __launch_bounds__(128) void scan2_kernel(int* __restrict__ aux, int nb)
{
    __shared__ int sh[128];
    int t = threadIdx.x;
    sh[t] = (t < nb) ? aux[t] : 0;
    __syncthreads();
#pragma unroll
    for (int off = 1; off < 128; off <<= 1) {
        int val = (t >= off) ? sh[t - off] : 0;
        __syncthreads();
        sh[t] += val;
        __syncthreads();
    }
    if (t < nb) aux[t] = sh[t];
}

__global__ __launch_bounds__(256) void scan3_kernel(int* __restrict__ R,
                                                    const int* __restrict__ aux, int n)
{
    int b = blockIdx.x + 1;               // blocks 1..NB-1
    int add = aux[b - 1];
#pragma unroll
    for (int i = 0; i < 4; ++i) {
        int idx = b * 1024 + threadIdx.x * 4 + i;
        if (idx < n) R[idx] += add;
    }
}

// Phase 3: fill. pos = R[dst]++ ; csr[pos] = e. Afterwards R[d] = end-of-d.
__global__ __launch_bounds__(256) void fill_kernel(
    const int* __restrict__ ei, int* __restrict__ R, int* __restrict__ csr)
{
    int e = blockIdx.x * 256 + threadIdx.x;
    if (e >= EE) return;
    int pos = atomicAdd(&R[ei[EE + e]], 1);
    csr[pos] = e;
}

// ============================ embedding ====================================
__global__ __launch_bounds__(256) void embed_kernel(
    const int* __restrict__ x_idx, const float* __restrict__ node_emb,
    float* __restrict__ x)
{
    int t = blockIdx.x * 256 + threadIdx.x;
    int node = t >> 5, j = t & 31;
    if (node >= NN) return;
    ((float4*)x)[node * 32 + j] =
        ((const float4*)node_emb)[x_idx[node] * 32 + j];
}

// ====================== gather aggregation (CSR) ===========================
// One 64-lane wave per node; lane owns float2 of the 128 features.
// agg[n] = sum_{e: dst(e)=n} relu(x[src(e)] + e1[a0]+e2[a1]+e3[a2])
__global__ __launch_bounds__(256) void gather_kernel(
    const float* __restrict__ x, const int* __restrict__ ei,
    const int* __restrict__ ea, const float* __restrict__ e1,
    const float* __restrict__ e2, const float* __restrict__ e3,
    const int* __restrict__ rowend, const int* __restrict__ csr,
    float* __restrict__ agg)
{
    int wid  = (blockIdx.x * 256 + threadIdx.x) >> 6;   // node
    int lane = threadIdx.x & 63;
    if (wid >= NN) return;
    int beg = (wid == 0) ? 0 : rowend[wid - 1];
    int end = rowend[wid];

    float2 acc = make_float2(0.f, 0.f);
    for (int p = beg; p < end; ++p) {
        int eid = csr[p];
        int src = ei[eid];
        int a0 = ea[eid * 3], a1 = ea[eid * 3 + 1], a2 = ea[eid * 3 + 2];
        float2 v  = ((const float2*)x )[src * 64 + lane];
        float2 w1 = ((const float2*)e1)[a0  * 64 + lane];
        float2 w2 = ((const float2*)e2)[a1  * 64 + lane];
        float2 w3 = ((const float2*)e3)[a2  * 64 + lane];
        acc.x += fmaxf(v.x + w1.x + w2.x + w3.x, 0.f);
        acc.y += fmaxf(v.y + w1.y + w2.y + w3.y, 0.f);
    }
    ((float2*)agg)[wid * 64 + lane] = acc;
}

// =================== fallback atomic edge scatter ==========================
__global__ __launch_bounds__(256) void edge_kernel(
    const float* __restrict__ x, const int* __restrict__ ei,
    const int* __restrict__ ea, const float* __restrict__ e1,
    const float* __restrict__ e2, const float* __restrict__ e3,
    float* __restrict__ agg)
{
    int t = blockIdx.x * 256 + threadIdx.x;
    int e = t >> 5, j = t & 31;
    if (e >= EE) return;
    int src = ei[e];
    int dst = ei[EE + e];
    int a0 = ea[e * 3 + 0], a1 = ea[e * 3 + 1], a2 = ea[e * 3 + 2];
    float4 v  = ((const float4*)x )[src * 32 + j];
    float4 w1 = ((const float4*)e1)[a0  * 32 + j];
    float4 w2 = ((const float4*)e2)[a1  * 32 + j];
    float4 w3 = ((const float4*)e3)[a2  * 32 + j];
    float mx = fmaxf(v.x + w1.x + w2.x + w3.x, 0.f);
    float my = fmaxf(v.y + w1.y + w2.y + w3.y, 0.f);
    float mz = fmaxf(v.z + w1.z + w2.z + w3.z, 0.f);
    float mw = fmaxf(v.w + w1.w + w2.w + w3.w, 0.f);
    float* ag = agg + (size_t)dst * HID + j * 4;
    atomicAdd(ag + 0, mx);
    atomicAdd(ag + 1, my);
    atomicAdd(ag + 2, mz);
    atomicAdd(ag + 3, mw);
}

// ============================ GEMM kernels =================================
// t = relu((x + agg) @ W + b). 32-row tile, 4x4 micro-tile/thread.
__global__ __launch_bounds__(256) void gemm_relu_kernel(
    const float* __restrict__ x, const float* __restrict__ agg,
    const float* __restrict__ W, const float* __restrict__ bias,
    float* __restrict__ t)
{
    __shared__ float h_s[32 * 129];
    int tid = threadIdx.x;
    int tc = tid & 31;
    int tr = tid >> 5;
    int rbase = blockIdx.x * 32;

    for (int idx = tid; idx < 32 * 128; idx += 256) {
        int r = idx >> 7, k = idx & 127;
        int g = (rbase + r) * HID + k;
        h_s[r * 129 + k] = x[g] + agg[g];
    }
    __syncthreads();

    float acc[4][4] = {};
    const float4* W4 = (const float4*)W;
#pragma unroll 4
    for (int k = 0; k < 128; ++k) {
        float4 w = W4[k * 32 + tc];
#pragma unroll
        for (int j = 0; j < 4; ++j) {
            float hv = h_s[(tr * 4 + j) * 129 + k];
            acc[j][0] = fmaf(hv, w.x, acc[j][0]);
            acc[j][1] = fmaf(hv, w.y, acc[j][1]);
            acc[j][2] = fmaf(hv, w.z, acc[j][2]);
            acc[j][3] = fmaf(hv, w.w, acc[j][3]);
        }
    }
    float4 bv = ((const float4*)bias)[tc];
#pragma unroll
    for (int j = 0; j < 4; ++j) {
        int r = rbase + tr * 4 + j;
        float4 o;
        o.x = fmaxf(acc[j][0] + bv.x, 0.f);
        o.y = fmaxf(acc[j][1] + bv.y, 0.f);
        o.z = fmaxf(acc[j][2] + bv.z, 0.f);
        o.w = fmaxf(acc[j][3] + bv.w, 0.f);
        ((float4*)t)[r * 32 + tc] = o;
    }
}

// u = t @ W + b;  x += relu(LN(u))
__global__ __launch_bounds__(256) void gemm_ln_res_kernel(
    const float* __restrict__ t, const float* __restrict__ W,
    const float* __restrict__ bias, const float* __restrict__ gamma,
    const float* __restrict__ beta, float* __restrict__ x)
{
    __shared__ float h_s[32 * 129];
    int tid = threadIdx.x;
    int tc = tid & 31;
    int tr = tid >> 5;
    int rbase = blockIdx.x * 32;

    for (int idx = tid; idx < 32 * 128; idx += 256) {
        int r = idx >> 7, k = idx & 127;
        h_s[r * 129 + k] = t[(rbase + r) * HID + k];
    }
    __syncthreads();

    float acc[4][4] = {};
    const float4* W4 = (const float4*)W;
#pragma unroll 4
    for (int k = 0; k < 128; ++k) {
        float4 w = W4[k * 32 + tc];
#pragma unroll
        for (int j = 0; j < 4; ++j) {
            float hv = h_s[(tr * 4 + j) * 129 + k];
            acc[j][0] = fmaf(hv, w.x, acc[j][0]);
            acc[j][1] = fmaf(hv, w.y, acc[j][1]);
            acc[j][2] = fmaf(hv, w.z, acc[j][2]);
            acc[j][3] = fmaf(hv, w.w, acc[j][3]);
        }
    }
    float4 bv  = ((const float4*)bias )[tc];
    float4 gv  = ((const float4*)gamma)[tc];
    float4 btv = ((const float4*)beta )[tc];
#pragma unroll
    for (int j = 0; j < 4; ++j) {
        acc[j][0] += bv.x; acc[j][1] += bv.y;
        acc[j][2] += bv.z; acc[j][3] += bv.w;
        float s = acc[j][0] + acc[j][1] + acc[j][2] + acc[j][3];
        float q = acc[j][0]*acc[j][0] + acc[j][1]*acc[j][1]
                + acc[j][2]*acc[j][2] + acc[j][3]*acc[j][3];
#pragma unroll
        for (int off = 1; off < 32; off <<= 1) {
            s += __shfl_xor(s, off, 64);
            q += __shfl_xor(q, off, 64);
        }
        float m   = s * (1.f / 128.f);
        float var = q * (1.f / 128.f) - m * m;
        float rs  = rsqrtf(var + 1e-5f);

        int r = rbase + tr * 4 + j;
        float4 xo = ((float4*)x)[r * 32 + tc];
        float4 o;
        o.x = xo.x + fmaxf((acc[j][0] - m) * rs * gv.x + btv.x, 0.f);
        o.y = xo.y + fmaxf((acc[j][1] - m) * rs * gv.y + btv.y, 0.f);
        o.z = xo.z + fmaxf((acc[j][2] - m) * rs * gv.z + btv.z, 0.f);
        o.w = xo.w + fmaxf((acc[j][3] - m) * rs * gv.w + btv.w, 0.f);
        ((float4*)x)[r * 32 + tc] = o;
    }
}

// ============================ mean pool ====================================
__global__ __launch_bounds__(256) void pool_kernel(
    const float* __restrict__ x, const int* __restrict__ batch,
    float* __restrict__ sums, int* __restrict__ cnt)
{
    int t = blockIdx.x * 256 + threadIdx.x;
    int node = t >> 5, j = t & 31;
    if (node >= NN) return;
    int b = batch[node];
    float4 v = ((const float4*)x)[node * 32 + j];
    float* sp = sums + b * HID + j * 4;
    atomicAdd(sp + 0, v.x);
    atomicAdd(sp + 1, v.y);
    atomicAdd(sp + 2, v.z);
    atomicAdd(sp + 3, v.w);
    if (j == 0) atomicAdd(&cnt[b], 1);
}

// ============================ head =========================================
__global__ __launch_bounds__(128) void head_kernel(
    const float* __restrict__ sums, const int* __restrict__ cnt,
    const float* __restrict__ pW1, const float* __restrict__ pb1,
    const float* __restrict__ pW2, const float* __restrict__ pb2,
    const float* __restrict__ pg, const float* __restrict__ pbn,
    const float* __restrict__ oW, const float* __restrict__ ob,
    float* __restrict__ out)
{
    __shared__ float s0[128], s1[128], red[4];
    int b = blockIdx.x, c = threadIdx.x;

    float cn = fmaxf((float)cnt[b], 1.f);
    s0[c] = sums[b * HID + c] / cn;
    __syncthreads();

    float a = pb1[c];
#pragma unroll 4
    for (int k = 0; k < HID; ++k) a = fmaf(s0[k], pW1[k * HID + c], a);
    a = fmaxf(a, 0.f);
    s1[c] = a;
    __syncthreads();

    float u = pb2[c];
#pragma unroll 4
    for (int k = 0; k < HID; ++k) u = fmaf(s1[k], pW2[k * HID + c], u);

    float s = u, q = u * u;
#pragma unroll
    for (int off = 1; off < 64; off <<= 1) {
        s += __shfl_xor(s, off, 64);
        q += __shfl_xor(q, off, 64);
    }
    if ((c & 63) == 0) { red[(c >> 6) * 2] = s; red[(c >> 6) * 2 + 1] = q; }
    __syncthreads();
    float S = red[0] + red[2], Q = red[1] + red[3];
    float m = S * (1.f / 128.f);
    float var = Q * (1.f / 128.f) - m * m;
    float rs = rsqrtf(var + 1e-5f);
    float v = fmaxf((u - m) * rs * pg[c] + pbn[c], 0.f);

    float p = v * oW[c];
#pragma unroll
    for (int off = 1; off < 64; off <<= 1) p += __shfl_xor(p, off, 64);
    __syncthreads();
    if ((c & 63) == 0) red[c >> 6] = p;
    __syncthreads();
    if (c == 0) {
        float tot = red[0] + red[1] + ob[0];
        out[b] = 1.f / (1.f + expf(-tot));
    }
}

// ===========================================================================
extern "C" void kernel_launch(void* const* d_in, const int* in_sizes, int n_in,
                              void* d_out, int out_size, void* d_ws, size_t ws_size,
                              hipStream_t stream)
{
    const int*   x_idx    = (const int*)d_in[0];
    const int*   ei       = (const int*)d_in[1];
    const int*   ea       = (const int*)d_in[2];
    const int*   batch    = (const int*)d_in[3];
    const float* node_emb = (const float*)d_in[4];
    const float* e1       = (const float*)d_in[5];
    const float* e2       = (const float*)d_in[6];
    const float* e3       = (const float*)d_in[7];
    const float* W1       = (const float*)d_in[8];
    const float* b1       = (const float*)d_in[9];
    const float* W2       = (const float*)d_in[10];
    const float* b2       = (const float*)d_in[11];
    const float* lg       = (const float*)d_in[12];
    const float* lb       = (const float*)d_in[13];
    const float* pW1      = (const float*)d_in[14];
    const float* pb1      = (const float*)d_in[15];
    const float* pW2      = (const float*)d_in[16];
    const float* pb2      = (const float*)d_in[17];
    const float* pg       = (const float*)d_in[18];
    const float* pbn      = (const float*)d_in[19];
    const float* oW       = (const float*)d_in[20];
    const float* ob       = (const float*)d_in[21];
    float* out = (float*)d_out;

    // ---- workspace layout (all offsets 16B-aligned) ----
    char* base = (char*)d_ws;
    size_t Sx = (size_t)NN * HID * sizeof(float);           // 51.2 MB
    float* x    = (float*)(base);
    float* agg  = (float*)(base + Sx);                      // also t
    float* sums = (float*)(base + 2 * Sx);
    int*   cnt  = (int*)  (base + 2 * Sx + BB * HID * 4);
    int*   R    = (int*)  (base + 2 * Sx + BB * HID * 4 + 2048);
    int*   csr  = (int*)  ((char*)R + 400016);              // (NN+1)*4 padded
    int*   aux  = (int*)  ((char*)csr + (size_t)EE * 4);
    size_t need = ((char*)aux + 512) - base;

    bool use_csr = (ws_size >= need);

    embed_kernel<<<(NN * 32 + 255) / 256, 256, 0, stream>>>(x_idx, node_emb, x);

    if (use_csr) {
        const int n = NN + 1, NB = (n + 1023) / 1024;       // 98 blocks
        hipMemsetAsync(R, 0, (size_t)n * sizeof(int), stream);
        hist_kernel <<<(EE + 255) / 256, 256, 0, stream>>>(ei, R);
        scan1_kernel<<<NB, 256, 0, stream>>>(R, aux, n);
        scan2_kernel<<<1, 128, 0, stream>>>(aux, NB);
        scan3_kernel<<<NB - 1, 256, 0, stream>>>(R, aux, n);
        fill_kernel <<<(EE + 255) / 256, 256, 0, stream>>>(ei, R, csr);
    }

    for (int l = 0; l < LL; ++l) {
        if (use_csr) {
            gather_kernel<<<(NN * 64 + 255) / 256, 256, 0, stream>>>(
                x, ei, ea, e1, e2, e3, R, csr, agg);
        } else {
            hipMemsetAsync(agg, 0, Sx, stream);
            edge_kernel<<<(EE * 32 + 255) / 256, 256, 0, stream>>>(
                x, ei, ea, e1, e2, e3, agg);
        }
        gemm_relu_kernel<<<NN / 32, 256, 0, stream>>>(
            x, agg, W1 + l * HID * HID, b1 + l * HID, agg /* t aliases agg */);
        gemm_ln_res_kernel<<<NN / 32, 256, 0, stream>>>(
            agg, W2 + l * HID * HID, b2 + l * HID,
            lg + l * HID, lb + l * HID, x);
    }

    hipMemsetAsync(sums, 0,
                   (size_t)BB * HID * sizeof(float) + BB * sizeof(int), stream);
    pool_kernel<<<(NN * 32 + 255) / 256, 256, 0, stream>>>(x, batch, sums, cnt);
    head_kernel<<<BB, 128, 0, stream>>>(
        sums, cnt, pW1, pb1, pW2, pb2, pg, pbn, oW, ob, out);
}

// Round 4
// 1571.216 us; speedup vs baseline: 7.4873x; 1.4801x over previous
//
#include <hip/hip_runtime.h>

#define HID 128
#define NN  100000
#define EE  1600000
#define BB  512
#define LL  4

// ============================ CSR build ====================================
// R has NN+1 ints. Phase 1: R[dst+1]++ (histogram, offset by one).
__global__ __launch_bounds__(256) void hist_kernel(
    const int* __restrict__ ei, int* __restrict__ R)
{
    int e = blockIdx.x * 256 + threadIdx.x;
    if (e >= EE) return;
    atomicAdd(&R[ei[EE + e] + 1], 1);
}

// Phase 2: inclusive prefix scan of R[0..n) (3-kernel scan, 1024 elems/block)
__global__ __launch_bounds__(256) void scan1_kernel(int* __restrict__ R,
                                                    int* __restrict__ aux, int n)
{
    __shared__ int sh[256];
    int base = blockIdx.x * 1024;
    int t = threadIdx.x;
    int v[4]; int s = 0;
#pragma unroll
    for (int i = 0; i < 4; ++i) {
        int idx = base + t * 4 + i;
        v[i] = (idx < n) ? R[idx] : 0;
        s += v[i];
    }
    sh[t] = s; __syncthreads();
#pragma unroll
    for (int off = 1; off < 256; off <<= 1) {
        int val = (t >= off) ? sh[t - off] : 0;
        __syncthreads();
        sh[t] += val;
        __syncthreads();
    }
    int run = (t == 0) ? 0 : sh[t - 1];
#pragma unroll
    for (int i = 0; i < 4; ++i) {
        int idx = base + t * 4 + i;
        run += v[i];
        if (idx < n) R[idx] = run;
    }
    if (t == 255) aux[blockIdx.x] = sh[255];
}

__global__ __launch_bounds__(128) void scan2_kernel(int* __restrict__ aux, int nb)
{
    __shared__ int sh[128];
    int t = threadIdx.x;
    sh[t] = (t < nb) ? aux[t] : 0;
    __syncthreads();
#pragma unroll
    for (int off = 1; off < 128; off <<= 1) {
        int val = (t >= off) ? sh[t - off] : 0;
        __syncthreads();
        sh[t] += val;
        __syncthreads();
    }
    if (t < nb) aux[t] = sh[t];
}

__global__ __launch_bounds__(256) void scan3_kernel(int* __restrict__ R,
                                                    const int* __restrict__ aux, int n)
{
    int b = blockIdx.x + 1;               // blocks 1..NB-1
    int add = aux[b - 1];
#pragma unroll
    for (int i = 0; i < 4; ++i) {
        int idx = b * 1024 + threadIdx.x * 4 + i;
        if (idx < n) R[idx] += add;
    }
}

// Phase 3: fill with PACKED records: src(17b) | a0(5b) | a1(5b) | a2(5b).
// pos = R[dst]++ ; afterwards R[d] = end-of-d (rowend semantics).
__global__ __launch_bounds__(256) void fill_kernel(
    const int* __restrict__ ei, const int* __restrict__ ea,
    int* __restrict__ R, unsigned int* __restrict__ csr)
{
    int e = blockIdx.x * 256 + threadIdx.x;
    if (e >= EE) return;
    int pos = atomicAdd(&R[ei[EE + e]], 1);
    unsigned int rec = (unsigned int)ei[e]
                     | ((unsigned int)ea[e * 3 + 0] << 17)
                     | ((unsigned int)ea[e * 3 + 1] << 22)
                     | ((unsigned int)ea[e * 3 + 2] << 27);
    csr[pos] = rec;
}

// ============================ embedding ====================================
__global__ __launch_bounds__(256) void embed_kernel(
    const int* __restrict__ x_idx, const float* __restrict__ node_emb,
    float* __restrict__ x)
{
    int t = blockIdx.x * 256 + threadIdx.x;
    int node = t >> 5, j = t & 31;
    if (node >= NN) return;
    ((float4*)x)[node * 32 + j] =
        ((const float4*)node_emb)[x_idx[node] * 32 + j];
}

// ====================== gather aggregation (CSR) ===========================
// One wave per node; 2 edges processed concurrently (32 lanes x float4 each),
// unrolled x2 -> up to 4 independent x-row fetches in flight per wave.
__device__ __forceinline__ float4 edge_term(
    unsigned int rec, int l32, const float* __restrict__ x,
    const float* __restrict__ e1, const float* __restrict__ e2,
    const float* __restrict__ e3)
{
    int src = rec & 0x1FFFF;
    int i0 = (rec >> 17) & 31, i1 = (rec >> 22) & 31, i2 = (rec >> 27) & 31;
    float4 v  = ((const float4*)x )[src * 32 + l32];
    float4 w1 = ((const float4*)e1)[i0  * 32 + l32];
    float4 w2 = ((const float4*)e2)[i1  * 32 + l32];
    float4 w3 = ((const float4*)e3)[i2  * 32 + l32];
    float4 r;
    r.x = fmaxf(v.x + w1.x + w2.x + w3.x, 0.f);
    r.y = fmaxf(v.y + w1.y + w2.y + w3.y, 0.f);
    r.z = fmaxf(v.z + w1.z + w2.z + w3.z, 0.f);
    r.w = fmaxf(v.w + w1.w + w2.w + w3.w, 0.f);
    return r;
}

__global__ __launch_bounds__(256) void gather_kernel(
    const float* __restrict__ x,
    const float* __restrict__ e1, const float* __restrict__ e2,
    const float* __restrict__ e3,
    const int* __restrict__ rowend, const unsigned int* __restrict__ csr,
    float* __restrict__ agg)
{
    int wid  = (blockIdx.x * 256 + threadIdx.x) >> 6;   // node
    int lane = threadIdx.x & 63;
    int half = lane >> 5;                               // which edge of the pair
    int l32  = lane & 31;                               // float4 slot in row
    if (wid >= NN) return;
    int beg = (wid == 0) ? 0 : rowend[wid - 1];
    int end = rowend[wid];

    float4 a0 = make_float4(0.f, 0.f, 0.f, 0.f);
    float4 a1 = make_float4(0.f, 0.f, 0.f, 0.f);
    int p = beg + half;
    for (; p + 2 < end; p += 4) {
        unsigned int r0 = csr[p];
        unsigned int r1 = csr[p + 2];
        float4 t0 = edge_term(r0, l32, x, e1, e2, e3);
        float4 t1 = edge_term(r1, l32, x, e1, e2, e3);
        a0.x += t0.x; a0.y += t0.y; a0.z += t0.z; a0.w += t0.w;
        a1.x += t1.x; a1.y += t1.y; a1.z += t1.z; a1.w += t1.w;
    }
    if (p < end) {
        float4 t0 = edge_term(csr[p], l32, x, e1, e2, e3);
        a0.x += t0.x; a0.y += t0.y; a0.z += t0.z; a0.w += t0.w;
    }
    float4 acc;
    acc.x = a0.x + a1.x; acc.y = a0.y + a1.y;
    acc.z = a0.z + a1.z; acc.w = a0.w + a1.w;
    // combine the two halves (edge-pair partial sums) across lane^32
    acc.x += __shfl_xor(acc.x, 32);
    acc.y += __shfl_xor(acc.y, 32);
    acc.z += __shfl_xor(acc.z, 32);
    acc.w += __shfl_xor(acc.w, 32);
    if (half == 0)
        ((float4*)agg)[wid * 32 + l32] = acc;
}

// =================== fallback atomic edge scatter ==========================
__global__ __launch_bounds__(256) void edge_kernel(
    const float* __restrict__ x, const int* __restrict__ ei,
    const int* __restrict__ ea, const float* __restrict__ e1,
    const float* __restrict__ e2, const float* __restrict__ e3,
    float* __restrict__ agg)
{
    int t = blockIdx.x * 256 + threadIdx.x;
    int e = t >> 5, j = t & 31;
    if (e >= EE) return;
    int src = ei[e];
    int dst = ei[EE + e];
    int a0 = ea[e * 3 + 0], a1 = ea[e * 3 + 1], a2 = ea[e * 3 + 2];
    float4 v  = ((const float4*)x )[src * 32 + j];
    float4 w1 = ((const float4*)e1)[a0  * 32 + j];
    float4 w2 = ((const float4*)e2)[a1  * 32 + j];
    float4 w3 = ((const float4*)e3)[a2  * 32 + j];
    float mx = fmaxf(v.x + w1.x + w2.x + w3.x, 0.f);
    float my = fmaxf(v.y + w1.y + w2.y + w3.y, 0.f);
    float mz = fmaxf(v.z + w1.z + w2.z + w3.z, 0.f);
    float mw = fmaxf(v.w + w1.w + w2.w + w3.w, 0.f);
    float* ag = agg + (size_t)dst * HID + j * 4;
    atomicAdd(ag + 0, mx);
    atomicAdd(ag + 1, my);
    atomicAdd(ag + 2, mz);
    atomicAdd(ag + 3, mw);
}

// ======================= fused layer MLP ===================================
// h = x + agg; t = relu(h@W1+b1); u = t@W2+b2; x += relu(LN(u,g,bt))
// Block: 256 threads, 32-row tile, 4x4 micro-tile per thread, t kept in LDS.
__global__ __launch_bounds__(256) void mlp_fused_kernel(
    const float* __restrict__ xin, const float* __restrict__ agg,
    const float* __restrict__ W1, const float* __restrict__ b1,
    const float* __restrict__ W2, const float* __restrict__ b2,
    const float* __restrict__ gamma, const float* __restrict__ beta,
    float* __restrict__ x)
{
    __shared__ float h_s[32 * 129];
    __shared__ float t_s[32 * 129];
    int tid = threadIdx.x;
    int tc = tid & 31;          // cols 4*tc..4*tc+3
    int tr = tid >> 5;          // rows 4*tr..4*tr+3
    int rbase = blockIdx.x * 32;

    // stage h = x + agg (float4 global reads)
    for (int idx = tid; idx < 32 * 32; idx += 256) {
        int r = idx >> 5, k4 = idx & 31;
        float4 xv = ((const float4*)xin)[(rbase + r) * 32 + k4];
        float4 av = ((const float4*)agg)[(rbase + r) * 32 + k4];
        float* d = &h_s[r * 129 + k4 * 4];
        d[0] = xv.x + av.x; d[1] = xv.y + av.y;
        d[2] = xv.z + av.z; d[3] = xv.w + av.w;
    }
    __syncthreads();

    // GEMM1 + bias + relu -> t_s
    {
        float acc[4][4] = {};
        const float4* W4 = (const float4*)W1;
#pragma unroll 4
        for (int k = 0; k < 128; ++k) {
            float4 w = W4[k * 32 + tc];
#pragma unroll
            for (int j = 0; j < 4; ++j) {
                float hv = h_s[(tr * 4 + j) * 129 + k];
                acc[j][0] = fmaf(hv, w.x, acc[j][0]);
                acc[j][1] = fmaf(hv, w.y, acc[j][1]);
                acc[j][2] = fmaf(hv, w.z, acc[j][2]);
                acc[j][3] = fmaf(hv, w.w, acc[j][3]);
            }
        }
        float4 bv = ((const float4*)b1)[tc];
#pragma unroll
        for (int j = 0; j < 4; ++j) {
            float* d = &t_s[(tr * 4 + j) * 129 + tc * 4];
            d[0] = fmaxf(acc[j][0] + bv.x, 0.f);
            d[1] = fmaxf(acc[j][1] + bv.y, 0.f);
            d[2] = fmaxf(acc[j][2] + bv.z, 0.f);
            d[3] = fmaxf(acc[j][3] + bv.w, 0.f);
        }
    }
    __syncthreads();

    // GEMM2 + bias + LN + relu + residual
    {
        float acc[4][4] = {};
        const float4* W4 = (const float4*)W2;
#pragma unroll 4
        for (int k = 0; k < 128; ++k) {
            float4 w = W4[k * 32 + tc];
#pragma unroll
            for (int j = 0; j < 4; ++j) {
                float hv = t_s[(tr * 4 + j) * 129 + k];
                acc[j][0] = fmaf(hv, w.x, acc[j][0]);
                acc[j][1] = fmaf(hv, w.y, acc[j][1]);
                acc[j][2] = fmaf(hv, w.z, acc[j][2]);
                acc[j][3] = fmaf(hv, w.w, acc[j][3]);
            }
        }
        float4 bv  = ((const float4*)b2  )[tc];
        float4 gv  = ((const float4*)gamma)[tc];
        float4 btv = ((const float4*)beta )[tc];
#pragma unroll
        for (int j = 0; j < 4; ++j) {
            acc[j][0] += bv.x; acc[j][1] += bv.y;
            acc[j][2] += bv.z; acc[j][3] += bv.w;
            float s = acc[j][0] + acc[j][1] + acc[j][2] + acc[j][3];
            float q = acc[j][0]*acc[j][0] + acc[j][1]*acc[j][1]
                    + acc[j][2]*acc[j][2] + acc[j][3]*acc[j][3];
            // reduce across the 32 tc-lanes (rows live in 32-lane half-waves)
#pragma unroll
            for (int off = 1; off < 32; off <<= 1) {
                s += __shfl_xor(s, off, 64);
                q += __shfl_xor(q, off, 64);
            }
            float m   = s * (1.f / 128.f);
            float var = q * (1.f / 128.f) - m * m;
            float rs  = rsqrtf(var + 1e-5f);

            int r = rbase + tr * 4 + j;
            float4 xo = ((float4*)x)[r * 32 + tc];
            float4 o;
            o.x = xo.x + fmaxf((acc[j][0] - m) * rs * gv.x + btv.x, 0.f);
            o.y = xo.y + fmaxf((acc[j][1] - m) * rs * gv.y + btv.y, 0.f);
            o.z = xo.z + fmaxf((acc[j][2] - m) * rs * gv.z + btv.z, 0.f);
            o.w = xo.w + fmaxf((acc[j][3] - m) * rs * gv.w + btv.w, 0.f);
            ((float4*)x)[r * 32 + tc] = o;
        }
    }
}

// ============== fallback split GEMMs (non-CSR path only) ===================
__global__ __launch_bounds__(256) void gemm_relu_kernel(
    const float* __restrict__ x, const float* __restrict__ agg,
    const float* __restrict__ W, const float* __restrict__ bias,
    float* __restrict__ t)
{
    __shared__ float h_s[32 * 129];
    int tid = threadIdx.x;
    int tc = tid & 31, tr = tid >> 5;
    int rbase = blockIdx.x * 32;
    for (int idx = tid; idx < 32 * 128; idx += 256) {
        int r = idx >> 7, k = idx & 127;
        int g = (rbase + r) * HID + k;
        h_s[r * 129 + k] = x[g] + agg[g];
    }
    __syncthreads();
    float acc[4][4] = {};
    const float4* W4 = (const float4*)W;
#pragma unroll 4
    for (int k = 0; k < 128; ++k) {
        float4 w = W4[k * 32 + tc];
#pragma unroll
        for (int j = 0; j < 4; ++j) {
            float hv = h_s[(tr * 4 + j) * 129 + k];
            acc[j][0] = fmaf(hv, w.x, acc[j][0]);
            acc[j][1] = fmaf(hv, w.y, acc[j][1]);
            acc[j][2] = fmaf(hv, w.z, acc[j][2]);
            acc[j][3] = fmaf(hv, w.w, acc[j][3]);
        }
    }
    float4 bv = ((const float4*)bias)[tc];
#pragma unroll
    for (int j = 0; j < 4; ++j) {
        int r = rbase + tr * 4 + j;
        float4 o;
        o.x = fmaxf(acc[j][0] + bv.x, 0.f);
        o.y = fmaxf(acc[j][1] + bv.y, 0.f);
        o.z = fmaxf(acc[j][2] + bv.z, 0.f);
        o.w = fmaxf(acc[j][3] + bv.w, 0.f);
        ((float4*)t)[r * 32 + tc] = o;
    }
}

__global__ __launch_bounds__(256) void gemm_ln_res_kernel(
    const float* __restrict__ t, const float* __restrict__ W,
    const float* __restrict__ bias, const float* __restrict__ gamma,
    const float* __restrict__ beta, float* __restrict__ x)
{
    __shared__ float h_s[32 * 129];
    int tid = threadIdx.x;
    int tc = tid & 31, tr = tid >> 5;
    int rbase = blockIdx.x * 32;
    for (int idx = tid; idx < 32 * 128; idx += 256) {
        int r = idx >> 7, k = idx & 127;
        h_s[r * 129 + k] = t[(rbase + r) * HID + k];
    }
    __syncthreads();
    float acc[4][4] = {};
    const float4* W4 = (const float4*)W;
#pragma unroll 4
    for (int k = 0; k < 128; ++k) {
        float4 w = W4[k * 32 + tc];
#pragma unroll
        for (int j = 0; j < 4; ++j) {
            float hv = h_s[(tr * 4 + j) * 129 + k];
            acc[j][0] = fmaf(hv, w.x, acc[j][0]);
            acc[j][1] = fmaf(hv, w.y, acc[j][1]);
            acc[j][2] = fmaf(hv, w.z, acc[j][2]);
            acc[j][3] = fmaf(hv, w.w, acc[j][3]);
        }
    }
    float4 bv  = ((const float4*)bias )[tc];
    float4 gv  = ((const float4*)gamma)[tc];
    float4 btv = ((const float4*)beta )[tc];
#pragma unroll
    for (int j = 0; j < 4; ++j) {
        acc[j][0] += bv.x; acc[j][1] += bv.y;
        acc[j][2] += bv.z; acc[j][3] += bv.w;
        float s = acc[j][0] + acc[j][1] + acc[j][2] + acc[j][3];
        float q = acc[j][0]*acc[j][0] + acc[j][1]*acc[j][1]
                + acc[j][2]*acc[j][2] + acc[j][3]*acc[j][3];
#pragma unroll
        for (int off = 1; off < 32; off <<= 1) {
            s += __shfl_xor(s, off, 64);
            q += __shfl_xor(q, off, 64);
        }
        float m   = s * (1.f / 128.f);
        float var = q * (1.f / 128.f) - m * m;
        float rs  = rsqrtf(var + 1e-5f);
        int r = rbase + tr * 4 + j;
        float4 xo = ((float4*)x)[r * 32 + tc];
        float4 o;
        o.x = xo.x + fmaxf((acc[j][0] - m) * rs * gv.x + btv.x, 0.f);
        o.y = xo.y + fmaxf((acc[j][1] - m) * rs * gv.y + btv.y, 0.f);
        o.z = xo.z + fmaxf((acc[j][2] - m) * rs * gv.z + btv.z, 0.f);
        o.w = xo.w + fmaxf((acc[j][3] - m) * rs * gv.w + btv.w, 0.f);
        ((float4*)x)[r * 32 + tc] = o;
    }
}

// ============================ mean pool ====================================
__global__ __launch_bounds__(256) void pool_kernel(
    const float* __restrict__ x, const int* __restrict__ batch,
    float* __restrict__ sums, int* __restrict__ cnt)
{
    int t = blockIdx.x * 256 + threadIdx.x;
    int node = t >> 5, j = t & 31;
    if (node >= NN) return;
    int b = batch[node];
    float4 v = ((const float4*)x)[node * 32 + j];
    float* sp = sums + b * HID + j * 4;
    atomicAdd(sp + 0, v.x);
    atomicAdd(sp + 1, v.y);
    atomicAdd(sp + 2, v.z);
    atomicAdd(sp + 3, v.w);
    if (j == 0) atomicAdd(&cnt[b], 1);
}

// ============================ head =========================================
__global__ __launch_bounds__(128) void head_kernel(
    const float* __restrict__ sums, const int* __restrict__ cnt,
    const float* __restrict__ pW1, const float* __restrict__ pb1,
    const float* __restrict__ pW2, const float* __restrict__ pb2,
    const float* __restrict__ pg, const float* __restrict__ pbn,
    const float* __restrict__ oW, const float* __restrict__ ob,
    float* __restrict__ out)
{
    __shared__ float s0[128], s1[128], red[4];
    int b = blockIdx.x, c = threadIdx.x;

    float cn = fmaxf((float)cnt[b], 1.f);
    s0[c] = sums[b * HID + c] / cn;
    __syncthreads();

    float a = pb1[c];
#pragma unroll 4
    for (int k = 0; k < HID; ++k) a = fmaf(s0[k], pW1[k * HID + c], a);
    a = fmaxf(a, 0.f);
    s1[c] = a;
    __syncthreads();

    float u = pb2[c];
#pragma unroll 4
    for (int k = 0; k < HID; ++k) u = fmaf(s1[k], pW2[k * HID + c], u);

    float s = u, q = u * u;
#pragma unroll
    for (int off = 1; off < 64; off <<= 1) {
        s += __shfl_xor(s, off, 64);
        q += __shfl_xor(q, off, 64);
    }
    if ((c & 63) == 0) { red[(c >> 6) * 2] = s; red[(c >> 6) * 2 + 1] = q; }
    __syncthreads();
    float S = red[0] + red[2], Q = red[1] + red[3];
    float m = S * (1.f / 128.f);
    float var = Q * (1.f / 128.f) - m * m;
    float rs = rsqrtf(var + 1e-5f);
    float v = fmaxf((u - m) * rs * pg[c] + pbn[c], 0.f);

    float p = v * oW[c];
#pragma unroll
    for (int off = 1; off < 64; off <<= 1) p += __shfl_xor(p, off, 64);
    __syncthreads();
    if ((c & 63) == 0) red[c >> 6] = p;
    __syncthreads();
    if (c == 0) {
        float tot = red[0] + red[1] + ob[0];
        out[b] = 1.f / (1.f + expf(-tot));
    }
}

// ===========================================================================
extern "C" void kernel_launch(void* const* d_in, const int* in_sizes, int n_in,
                              void* d_out, int out_size, void* d_ws, size_t ws_size,
                              hipStream_t stream)
{
    const int*   x_idx    = (const int*)d_in[0];
    const int*   ei       = (const int*)d_in[1];
    const int*   ea       = (const int*)d_in[2];
    const int*   batch    = (const int*)d_in[3];
    const float* node_emb = (const float*)d_in[4];
    const float* e1       = (const float*)d_in[5];
    const float* e2       = (const float*)d_in[6];
    const float* e3       = (const float*)d_in[7];
    const float* W1       = (const float*)d_in[8];
    const float* b1       = (const float*)d_in[9];
    const float* W2       = (const float*)d_in[10];
    const float* b2       = (const float*)d_in[11];
    const float* lg       = (const float*)d_in[12];
    const float* lb       = (const float*)d_in[13];
    const float* pW1      = (const float*)d_in[14];
    const float* pb1      = (const float*)d_in[15];
    const float* pW2      = (const float*)d_in[16];
    const float* pb2      = (const float*)d_in[17];
    const float* pg       = (const float*)d_in[18];
    const float* pbn      = (const float*)d_in[19];
    const float* oW       = (const float*)d_in[20];
    const float* ob       = (const float*)d_in[21];
    float* out = (float*)d_out;

    // ---- workspace layout (all offsets 16B-aligned) ----
    char* base = (char*)d_ws;
    size_t Sx = (size_t)NN * HID * sizeof(float);           // 51.2 MB
    float* x    = (float*)(base);
    float* agg  = (float*)(base + Sx);                      // also t (fallback)
    float* sums = (float*)(base + 2 * Sx);
    int*   cnt  = (int*)  (base + 2 * Sx + BB * HID * 4);
    int*   R    = (int*)  (base + 2 * Sx + BB * HID * 4 + 2048);
    unsigned int* csr = (unsigned int*)((char*)R + 400016); // (NN+1)*4 padded
    int*   aux  = (int*)  ((char*)csr + (size_t)EE * 4);
    size_t need = ((char*)aux + 512) - base;

    bool use_csr = (ws_size >= need);

    embed_kernel<<<(NN * 32 + 255) / 256, 256, 0, stream>>>(x_idx, node_emb, x);

    if (use_csr) {
        const int n = NN + 1, NB = (n + 1023) / 1024;       // 98 blocks
        hipMemsetAsync(R, 0, (size_t)n * sizeof(int), stream);
        hist_kernel <<<(EE + 255) / 256, 256, 0, stream>>>(ei, R);
        scan1_kernel<<<NB, 256, 0, stream>>>(R, aux, n);
        scan2_kernel<<<1, 128, 0, stream>>>(aux, NB);
        scan3_kernel<<<NB - 1, 256, 0, stream>>>(R, aux, n);
        fill_kernel <<<(EE + 255) / 256, 256, 0, stream>>>(ei, ea, R, csr);
    }

    for (int l = 0; l < LL; ++l) {
        if (use_csr) {
            gather_kernel<<<(NN * 64 + 255) / 256, 256, 0, stream>>>(
                x, e1, e2, e3, R, csr, agg);
            mlp_fused_kernel<<<NN / 32, 256, 0, stream>>>(
                x, agg, W1 + l * HID * HID, b1 + l * HID,
                W2 + l * HID * HID, b2 + l * HID,
                lg + l * HID, lb + l * HID, x);
        } else {
            hipMemsetAsync(agg, 0, Sx, stream);
            edge_kernel<<<(EE * 32 + 255) / 256, 256, 0, stream>>>(
                x, ei, ea, e1, e2, e3, agg);
            gemm_relu_kernel<<<NN / 32, 256, 0, stream>>>(
                x, agg, W1 + l * HID * HID, b1 + l * HID, agg);
            gemm_ln_res_kernel<<<NN / 32, 256, 0, stream>>>(
                agg, W2 + l * HID * HID, b2 + l * HID,
                lg + l * HID, lb + l * HID, x);
        }
    }

    hipMemsetAsync(sums, 0,
                   (size_t)BB * HID * sizeof(float) + BB * sizeof(int), stream);
    pool_kernel<<<(NN * 32 + 255) / 256, 256, 0, stream>>>(x, batch, sums, cnt);
    head_kernel<<<BB, 128, 0, stream>>>(
        sums, cnt, pW1, pb1, pW2, pb2, pg, pbn, oW, ob, out);
}

// Round 6
// 1338.434 us; speedup vs baseline: 8.7895x; 1.1739x over previous
//
#include <hip/hip_runtime.h>

#define HID 128
#define NN  100000
#define EE  1600000
#define BB  512
#define LL  4

// ============================ CSR build ====================================
__global__ __launch_bounds__(256) void hist_kernel(
    const int* __restrict__ ei, int* __restrict__ R)
{
    int e = blockIdx.x * 256 + threadIdx.x;
    if (e >= EE) return;
    atomicAdd(&R[ei[EE + e] + 1], 1);
}

__global__ __launch_bounds__(256) void scan1_kernel(int* __restrict__ R,
                                                    int* __restrict__ aux, int n)
{
    __shared__ int sh[256];
    int base = blockIdx.x * 1024;
    int t = threadIdx.x;
    int v[4]; int s = 0;
#pragma unroll
    for (int i = 0; i < 4; ++i) {
        int idx = base + t * 4 + i;
        v[i] = (idx < n) ? R[idx] : 0;
        s += v[i];
    }
    sh[t] = s; __syncthreads();
#pragma unroll
    for (int off = 1; off < 256; off <<= 1) {
        int val = (t >= off) ? sh[t - off] : 0;
        __syncthreads();
        sh[t] += val;
        __syncthreads();
    }
    int run = (t == 0) ? 0 : sh[t - 1];
#pragma unroll
    for (int i = 0; i < 4; ++i) {
        int idx = base + t * 4 + i;
        run += v[i];
        if (idx < n) R[idx] = run;
    }
    if (t == 255) aux[blockIdx.x] = sh[255];
}

__global__ __launch_bounds__(128) void scan2_kernel(int* __restrict__ aux, int nb)
{
    __shared__ int sh[128];
    int t = threadIdx.x;
    sh[t] = (t < nb) ? aux[t] : 0;
    __syncthreads();
#pragma unroll
    for (int off = 1; off < 128; off <<= 1) {
        int val = (t >= off) ? sh[t - off] : 0;
        __syncthreads();
        sh[t] += val;
        __syncthreads();
    }
    if (t < nb) aux[t] = sh[t];
}

__global__ __launch_bounds__(256) void scan3_kernel(int* __restrict__ R,
                                                    const int* __restrict__ aux, int n)
{
    int b = blockIdx.x + 1;
    int add = aux[b - 1];
#pragma unroll
    for (int i = 0; i < 4; ++i) {
        int idx = b * 1024 + threadIdx.x * 4 + i;
        if (idx < n) R[idx] += add;
    }
}

// fill with PACKED records: src(17b) | a0(5b) | a1(5b) | a2(5b)
__global__ __launch_bounds__(256) void fill_kernel(
    const int* __restrict__ ei, const int* __restrict__ ea,
    int* __restrict__ R, unsigned int* __restrict__ csr)
{
    int e = blockIdx.x * 256 + threadIdx.x;
    if (e >= EE) return;
    int pos = atomicAdd(&R[ei[EE + e]], 1);
    unsigned int rec = (unsigned int)ei[e]
                     | ((unsigned int)ea[e * 3 + 0] << 17)
                     | ((unsigned int)ea[e * 3 + 1] << 22)
                     | ((unsigned int)ea[e * 3 + 2] << 27);
    csr[pos] = rec;
}

// ============================ embedding ====================================
__global__ __launch_bounds__(256) void embed_kernel(
    const int* __restrict__ x_idx, const float* __restrict__ node_emb,
    float* __restrict__ x)
{
    int t = blockIdx.x * 256 + threadIdx.x;
    int node = t >> 5, j = t & 31;
    if (node >= NN) return;
    ((float4*)x)[node * 32 + j] =
        ((const float4*)node_emb)[x_idx[node] * 32 + j];
}

// ====================== gather aggregation (CSR) ===========================
// One wave per node; 2 edges concurrent (32 lanes x float4), unroll x4 ->
// 4 independent edge chains, ~16 outstanding loads per lane.
__device__ __forceinline__ float4 edge_term(
    unsigned int rec, int l32, const float* __restrict__ x,
    const float* __restrict__ e1, const float* __restrict__ e2,
    const float* __restrict__ e3)
{
    int src = rec & 0x1FFFF;
    int i0 = (rec >> 17) & 31, i1 = (rec >> 22) & 31, i2 = (rec >> 27) & 31;
    float4 v  = ((const float4*)x )[src * 32 + l32];
    float4 w1 = ((const float4*)e1)[i0  * 32 + l32];
    float4 w2 = ((const float4*)e2)[i1  * 32 + l32];
    float4 w3 = ((const float4*)e3)[i2  * 32 + l32];
    float4 r;
    r.x = fmaxf(v.x + w1.x + w2.x + w3.x, 0.f);
    r.y = fmaxf(v.y + w1.y + w2.y + w3.y, 0.f);
    r.z = fmaxf(v.z + w1.z + w2.z + w3.z, 0.f);
    r.w = fmaxf(v.w + w1.w + w2.w + w3.w, 0.f);
    return r;
}

__global__ __launch_bounds__(256) void gather_kernel(
    const float* __restrict__ x,
    const float* __restrict__ e1, const float* __restrict__ e2,
    const float* __restrict__ e3,
    const int* __restrict__ rowend, const unsigned int* __restrict__ csr,
    float* __restrict__ agg)
{
    int wid  = (blockIdx.x * 256 + threadIdx.x) >> 6;   // node
    int lane = threadIdx.x & 63;
    int half = lane >> 5;
    int l32  = lane & 31;
    if (wid >= NN) return;
    int beg = (wid == 0) ? 0 : rowend[wid - 1];
    int end = rowend[wid];

    float4 a0 = make_float4(0.f, 0.f, 0.f, 0.f);
    float4 a1 = make_float4(0.f, 0.f, 0.f, 0.f);
    float4 a2 = make_float4(0.f, 0.f, 0.f, 0.f);
    float4 a3 = make_float4(0.f, 0.f, 0.f, 0.f);
    int p = beg + half;
    // unroll x4: 8 edges per wave-iteration (4 per half)
    for (; p + 6 < end; p += 8) {
        unsigned int r0 = csr[p];
        unsigned int r1 = csr[p + 2];
        unsigned int r2 = csr[p + 4];
        unsigned int r3 = csr[p + 6];
        float4 t0 = edge_term(r0, l32, x, e1, e2, e3);
        float4 t1 = edge_term(r1, l32, x, e1, e2, e3);
        float4 t2 = edge_term(r2, l32, x, e1, e2, e3);
        float4 t3 = edge_term(r3, l32, x, e1, e2, e3);
        a0.x += t0.x; a0.y += t0.y; a0.z += t0.z; a0.w += t0.w;
        a1.x += t1.x; a1.y += t1.y; a1.z += t1.z; a1.w += t1.w;
        a2.x += t2.x; a2.y += t2.y; a2.z += t2.z; a2.w += t2.w;
        a3.x += t3.x; a3.y += t3.y; a3.z += t3.z; a3.w += t3.w;
    }
    for (; p < end; p += 2) {
        float4 t0 = edge_term(csr[p], l32, x, e1, e2, e3);
        a0.x += t0.x; a0.y += t0.y; a0.z += t0.z; a0.w += t0.w;
    }
    float4 acc;
    acc.x = (a0.x + a1.x) + (a2.x + a3.x);
    acc.y = (a0.y + a1.y) + (a2.y + a3.y);
    acc.z = (a0.z + a1.z) + (a2.z + a3.z);
    acc.w = (a0.w + a1.w) + (a2.w + a3.w);
    acc.x += __shfl_xor(acc.x, 32);
    acc.y += __shfl_xor(acc.y, 32);
    acc.z += __shfl_xor(acc.z, 32);
    acc.w += __shfl_xor(acc.w, 32);
    if (half == 0)
        ((float4*)agg)[wid * 32 + l32] = acc;
}

// =================== fallback atomic edge scatter ==========================
__global__ __launch_bounds__(256) void edge_kernel(
    const float* __restrict__ x, const int* __restrict__ ei,
    const int* __restrict__ ea, const float* __restrict__ e1,
    const float* __restrict__ e2, const float* __restrict__ e3,
    float* __restrict__ agg)
{
    int t = blockIdx.x * 256 + threadIdx.x;
    int e = t >> 5, j = t & 31;
    if (e >= EE) return;
    int src = ei[e];
    int dst = ei[EE + e];
    int a0 = ea[e * 3 + 0], a1 = ea[e * 3 + 1], a2 = ea[e * 3 + 2];
    float4 v  = ((const float4*)x )[src * 32 + j];
    float4 w1 = ((const float4*)e1)[a0  * 32 + j];
    float4 w2 = ((const float4*)e2)[a1  * 32 + j];
    float4 w3 = ((const float4*)e3)[a2  * 32 + j];
    float mx = fmaxf(v.x + w1.x + w2.x + w3.x, 0.f);
    float my = fmaxf(v.y + w1.y + w2.y + w3.y, 0.f);
    float mz = fmaxf(v.z + w1.z + w2.z + w3.z, 0.f);
    float mw = fmaxf(v.w + w1.w + w2.w + w3.w, 0.f);
    float* ag = agg + (size_t)dst * HID + j * 4;
    atomicAdd(ag + 0, mx);
    atomicAdd(ag + 1, my);
    atomicAdd(ag + 2, mz);
    atomicAdd(ag + 3, mw);
}

// ======================= fused layer MLP ===================================
// h = x + agg; t = relu(h@W1+b1); u = t@W2+b2; x += relu(LN(u,g,bt))
__global__ __launch_bounds__(256) void mlp_fused_kernel(
    const float* __restrict__ xin, const float* __restrict__ agg,
    const float* __restrict__ W1, const float* __restrict__ b1,
    const float* __restrict__ W2, const float* __restrict__ b2,
    const float* __restrict__ gamma, const float* __restrict__ beta,
    float* __restrict__ x)
{
    __shared__ float h_s[32 * 129];
    __shared__ float t_s[32 * 129];
    int tid = threadIdx.x;
    int tc = tid & 31;
    int tr = tid >> 5;
    int rbase = blockIdx.x * 32;

    for (int idx = tid; idx < 32 * 32; idx += 256) {
        int r = idx >> 5, k4 = idx & 31;
        float4 xv = ((const float4*)xin)[(rbase + r) * 32 + k4];
        float4 av = ((const float4*)agg)[(rbase + r) * 32 + k4];
        float* d = &h_s[r * 129 + k4 * 4];
        d[0] = xv.x + av.x; d[1] = xv.y + av.y;
        d[2] = xv.z + av.z; d[3] = xv.w + av.w;
    }
    __syncthreads();

    {
        float acc[4][4] = {};
        const float4* W4 = (const float4*)W1;
#pragma unroll 4
        for (int k = 0; k < 128; ++k) {
            float4 w = W4[k * 32 + tc];
#pragma unroll
            for (int j = 0; j < 4; ++j) {
                float hv = h_s[(tr * 4 + j) * 129 + k];
                acc[j][0] = fmaf(hv, w.x, acc[j][0]);
                acc[j][1] = fmaf(hv, w.y, acc[j][1]);
                acc[j][2] = fmaf(hv, w.z, acc[j][2]);
                acc[j][3] = fmaf(hv, w.w, acc[j][3]);
            }
        }
        float4 bv = ((const float4*)b1)[tc];
#pragma unroll
        for (int j = 0; j < 4; ++j) {
            float* d = &t_s[(tr * 4 + j) * 129 + tc * 4];
            d[0] = fmaxf(acc[j][0] + bv.x, 0.f);
            d[1] = fmaxf(acc[j][1] + bv.y, 0.f);
            d[2] = fmaxf(acc[j][2] + bv.z, 0.f);
            d[3] = fmaxf(acc[j][3] + bv.w, 0.f);
        }
    }
    __syncthreads();

    {
        float acc[4][4] = {};
        const float4* W4 = (const float4*)W2;
#pragma unroll 4
        for (int k = 0; k < 128; ++k) {
            float4 w = W4[k * 32 + tc];
#pragma unroll
            for (int j = 0; j < 4; ++j) {
                float hv = t_s[(tr * 4 + j) * 129 + k];
                acc[j][0] = fmaf(hv, w.x, acc[j][0]);
                acc[j][1] = fmaf(hv, w.y, acc[j][1]);
                acc[j][2] = fmaf(hv, w.z, acc[j][2]);
                acc[j][3] = fmaf(hv, w.w, acc[j][3]);
            }
        }
        float4 bv  = ((const float4*)b2  )[tc];
        float4 gv  = ((const float4*)gamma)[tc];
        float4 btv = ((const float4*)beta )[tc];
#pragma unroll
        for (int j = 0; j < 4; ++j) {
            acc[j][0] += bv.x; acc[j][1] += bv.y;
            acc[j][2] += bv.z; acc[j][3] += bv.w;
            float s = acc[j][0] + acc[j][1] + acc[j][2] + acc[j][3];
            float q = acc[j][0]*acc[j][0] + acc[j][1]*acc[j][1]
                    + acc[j][2]*acc[j][2] + acc[j][3]*acc[j][3];
#pragma unroll
            for (int off = 1; off < 32; off <<= 1) {
                s += __shfl_xor(s, off, 64);
                q += __shfl_xor(q, off, 64);
            }
            float m   = s * (1.f / 128.f);
            float var = q * (1.f / 128.f) - m * m;
            float rs  = rsqrtf(var + 1e-5f);

            int r = rbase + tr * 4 + j;
            float4 xo = ((float4*)x)[r * 32 + tc];
            float4 o;
            o.x = xo.x + fmaxf((acc[j][0] - m) * rs * gv.x + btv.x, 0.f);
            o.y = xo.y + fmaxf((acc[j][1] - m) * rs * gv.y + btv.y, 0.f);
            o.z = xo.z + fmaxf((acc[j][2] - m) * rs * gv.z + btv.z, 0.f);
            o.w = xo.w + fmaxf((acc[j][3] - m) * rs * gv.w + btv.w, 0.f);
            ((float4*)x)[r * 32 + tc] = o;
        }
    }
}

// ============== fallback split GEMMs (non-CSR path only) ===================
__global__ __launch_bounds__(256) void gemm_relu_kernel(
    const float* __restrict__ x, const float* __restrict__ agg,
    const float* __restrict__ W, const float* __restrict__ bias,
    float* __restrict__ t)
{
    __shared__ float h_s[32 * 129];
    int tid = threadIdx.x;
    int tc = tid & 31, tr = tid >> 5;
    int rbase = blockIdx.x * 32;
    for (int idx = tid; idx < 32 * 128; idx += 256) {
        int r = idx >> 7, k = idx & 127;
        int g = (rbase + r) * HID + k;
        h_s[r * 129 + k] = x[g] + agg[g];
    }
    __syncthreads();
    float acc[4][4] = {};
    const float4* W4 = (const float4*)W;
#pragma unroll 4
    for (int k = 0; k < 128; ++k) {
        float4 w = W4[k * 32 + tc];
#pragma unroll
        for (int j = 0; j < 4; ++j) {
            float hv = h_s[(tr * 4 + j) * 129 + k];
            acc[j][0] = fmaf(hv, w.x, acc[j][0]);
            acc[j][1] = fmaf(hv, w.y, acc[j][1]);
            acc[j][2] = fmaf(hv, w.z, acc[j][2]);
            acc[j][3] = fmaf(hv, w.w, acc[j][3]);
        }
    }
    float4 bv = ((const float4*)bias)[tc];
#pragma unroll
    for (int j = 0; j < 4; ++j) {
        int r = rbase + tr * 4 + j;
        float4 o;
        o.x = fmaxf(acc[j][0] + bv.x, 0.f);
        o.y = fmaxf(acc[j][1] + bv.y, 0.f);
        o.z = fmaxf(acc[j][2] + bv.z, 0.f);
        o.w = fmaxf(acc[j][3] + bv.w, 0.f);
        ((float4*)t)[r * 32 + tc] = o;
    }
}

__global__ __launch_bounds__(256) void gemm_ln_res_kernel(
    const float* __restrict__ t, const float* __restrict__ W,
    const float* __restrict__ bias, const float* __restrict__ gamma,
    const float* __restrict__ beta, float* __restrict__ x)
{
    __shared__ float h_s[32 * 129];
    int tid = threadIdx.x;
    int tc = tid & 31, tr = tid >> 5;
    int rbase = blockIdx.x * 32;
    for (int idx = tid; idx < 32 * 128; idx += 256) {
        int r = idx >> 7, k = idx & 127;
        h_s[r * 129 + k] = t[(rbase + r) * HID + k];
    }
    __syncthreads();
    float acc[4][4] = {};
    const float4* W4 = (const float4*)W;
#pragma unroll 4
    for (int k = 0; k < 128; ++k) {
        float4 w = W4[k * 32 + tc];
#pragma unroll
        for (int j = 0; j < 4; ++j) {
            float hv = h_s[(tr * 4 + j) * 129 + k];
            acc[j][0] = fmaf(hv, w.x, acc[j][0]);
            acc[j][1] = fmaf(hv, w.y, acc[j][1]);
            acc[j][2] = fmaf(hv, w.z, acc[j][2]);
            acc[j][3] = fmaf(hv, w.w, acc[j][3]);
        }
    }
    float4 bv  = ((const float4*)bias )[tc];
    float4 gv  = ((const float4*)gamma)[tc];
    float4 btv = ((const float4*)beta )[tc];
#pragma unroll
    for (int j = 0; j < 4; ++j) {
        acc[j][0] += bv.x; acc[j][1] += bv.y;
        acc[j][2] += bv.z; acc[j][3] += bv.w;
        float s = acc[j][0] + acc[j][1] + acc[j][2] + acc[j][3];
        float q = acc[j][0]*acc[j][0] + acc[j][1]*acc[j][1]
                + acc[j][2]*acc[j][2] + acc[j][3]*acc[j][3];
#pragma unroll
        for (int off = 1; off < 32; off <<= 1) {
            s += __shfl_xor(s, off, 64);
            q += __shfl_xor(q, off, 64);
        }
        float m   = s * (1.f / 128.f);
        float var = q * (1.f / 128.f) - m * m;
        float rs  = rsqrtf(var + 1e-5f);
        int r = rbase + tr * 4 + j;
        float4 xo = ((float4*)x)[r * 32 + tc];
        float4 o;
        o.x = xo.x + fmaxf((acc[j][0] - m) * rs * gv.x + btv.x, 0.f);
        o.y = xo.y + fmaxf((acc[j][1] - m) * rs * gv.y + btv.y, 0.f);
        o.z = xo.z + fmaxf((acc[j][2] - m) * rs * gv.z + btv.z, 0.f);
        o.w = xo.w + fmaxf((acc[j][3] - m) * rs * gv.w + btv.w, 0.f);
        ((float4*)x)[r * 32 + tc] = o;
    }
}

// ============================ mean pool ====================================
// batch is SORTED. One wave per 32-node chunk; lane owns float2 of features.
// Accumulate in registers while batch id constant; flush at run boundaries.
#define PCHUNK 32
__global__ __launch_bounds__(256) void pool_kernel(
    const float* __restrict__ x, const int* __restrict__ batch,
    float* __restrict__ sums, int* __restrict__ cnt)
{
    int wave = (blockIdx.x * 256 + threadIdx.x) >> 6;
    int lane = threadIdx.x & 63;
    int n0 = wave * PCHUNK;
    if (n0 >= NN) return;
    int n1 = n0 + PCHUNK; if (n1 > NN) n1 = NN;

    float2 acc = make_float2(0.f, 0.f);
    int cur = batch[n0];
    int run = 0;
    for (int n = n0; n < n1; ++n) {
        int b = batch[n];                      // wave-uniform
        if (b != cur) {
            float* sp = sums + cur * HID + lane * 2;
            atomicAdd(sp + 0, acc.x);
            atomicAdd(sp + 1, acc.y);
            if (lane == 0) atomicAdd(&cnt[cur], run);
            acc = make_float2(0.f, 0.f);
            run = 0; cur = b;
        }
        float2 v = ((const float2*)x)[(size_t)n * 64 + lane];
        acc.x += v.x; acc.y += v.y; ++run;
    }
    float* sp = sums + cur * HID + lane * 2;
    atomicAdd(sp + 0, acc.x);
    atomicAdd(sp + 1, acc.y);
    if (lane == 0) atomicAdd(&cnt[cur], run);
}

// ============================ head =========================================
__global__ __launch_bounds__(128) void head_kernel(
    const float* __restrict__ sums, const int* __restrict__ cnt,
    const float* __restrict__ pW1, const float* __restrict__ pb1,
    const float* __restrict__ pW2, const float* __restrict__ pb2,
    const float* __restrict__ pg, const float* __restrict__ pbn,
    const float* __restrict__ oW, const float* __restrict__ ob,
    float* __restrict__ out)
{
    __shared__ float s0[128], s1[128], red[4];
    int b = blockIdx.x, c = threadIdx.x;

    float cn = fmaxf((float)cnt[b], 1.f);
    s0[c] = sums[b * HID + c] / cn;
    __syncthreads();

    float a = pb1[c];
#pragma unroll 4
    for (int k = 0; k < HID; ++k) a = fmaf(s0[k], pW1[k * HID + c], a);
    a = fmaxf(a, 0.f);
    s1[c] = a;
    __syncthreads();

    float u = pb2[c];
#pragma unroll 4
    for (int k = 0; k < HID; ++k) u = fmaf(s1[k], pW2[k * HID + c], u);

    float s = u, q = u * u;
#pragma unroll
    for (int off = 1; off < 64; off <<= 1) {
        s += __shfl_xor(s, off, 64);
        q += __shfl_xor(q, off, 64);
    }
    if ((c & 63) == 0) { red[(c >> 6) * 2] = s; red[(c >> 6) * 2 + 1] = q; }
    __syncthreads();
    float S = red[0] + red[2], Q = red[1] + red[3];
    float m = S * (1.f / 128.f);
    float var = Q * (1.f / 128.f) - m * m;
    float rs = rsqrtf(var + 1e-5f);
    float v = fmaxf((u - m) * rs * pg[c] + pbn[c], 0.f);

    float p = v * oW[c];
#pragma unroll
    for (int off = 1; off < 64; off <<= 1) p += __shfl_xor(p, off, 64);
    __syncthreads();
    if ((c & 63) == 0) red[c >> 6] = p;
    __syncthreads();
    if (c == 0) {
        float tot = red[0] + red[1] + ob[0];
        out[b] = 1.f / (1.f + expf(-tot));
    }
}

// ===========================================================================
extern "C" void kernel_launch(void* const* d_in, const int* in_sizes, int n_in,
                              void* d_out, int out_size, void* d_ws, size_t ws_size,
                              hipStream_t stream)
{
    const int*   x_idx    = (const int*)d_in[0];
    const int*   ei       = (const int*)d_in[1];
    const int*   ea       = (const int*)d_in[2];
    const int*   batch    = (const int*)d_in[3];
    const float* node_emb = (const float*)d_in[4];
    const float* e1       = (const float*)d_in[5];
    const float* e2       = (const float*)d_in[6];
    const float* e3       = (const float*)d_in[7];
    const float* W1       = (const float*)d_in[8];
    const float* b1       = (const float*)d_in[9];
    const float* W2       = (const float*)d_in[10];
    const float* b2       = (const float*)d_in[11];
    const float* lg       = (const float*)d_in[12];
    const float* lb       = (const float*)d_in[13];
    const float* pW1      = (const float*)d_in[14];
    const float* pb1      = (const float*)d_in[15];
    const float* pW2      = (const float*)d_in[16];
    const float* pb2      = (const float*)d_in[17];
    const float* pg       = (const float*)d_in[18];
    const float* pbn      = (const float*)d_in[19];
    const float* oW       = (const float*)d_in[20];
    const float* ob       = (const float*)d_in[21];
    float* out = (float*)d_out;

    char* base = (char*)d_ws;
    size_t Sx = (size_t)NN * HID * sizeof(float);           // 51.2 MB
    float* x    = (float*)(base);
    float* agg  = (float*)(base + Sx);                      // also t (fallback)
    float* sums = (float*)(base + 2 * Sx);
    int*   cnt  = (int*)  (base + 2 * Sx + BB * HID * 4);
    int*   R    = (int*)  (base + 2 * Sx + BB * HID * 4 + 2048);
    unsigned int* csr = (unsigned int*)((char*)R + 400016);
    int*   aux  = (int*)  ((char*)csr + (size_t)EE * 4);
    size_t need = ((char*)aux + 512) - base;

    bool use_csr = (ws_size >= need);

    embed_kernel<<<(NN * 32 + 255) / 256, 256, 0, stream>>>(x_idx, node_emb, x);

    if (use_csr) {
        const int n = NN + 1, NB = (n + 1023) / 1024;
        hipMemsetAsync(R, 0, (size_t)n * sizeof(int), stream);
        hist_kernel <<<(EE + 255) / 256, 256, 0, stream>>>(ei, R);
        scan1_kernel<<<NB, 256, 0, stream>>>(R, aux, n);
        scan2_kernel<<<1, 128, 0, stream>>>(aux, NB);
        scan3_kernel<<<NB - 1, 256, 0, stream>>>(R, aux, n);
        fill_kernel <<<(EE + 255) / 256, 256, 0, stream>>>(ei, ea, R, csr);
    }

    for (int l = 0; l < LL; ++l) {
        if (use_csr) {
            gather_kernel<<<(NN * 64 + 255) / 256, 256, 0, stream>>>(
                x, e1, e2, e3, R, csr, agg);
            mlp_fused_kernel<<<NN / 32, 256, 0, stream>>>(
                x, agg, W1 + l * HID * HID, b1 + l * HID,
                W2 + l * HID * HID, b2 + l * HID,
                lg + l * HID, lb + l * HID, x);
        } else {
            hipMemsetAsync(agg, 0, Sx, stream);
            edge_kernel<<<(EE * 32 + 255) / 256, 256, 0, stream>>>(
                x, ei, ea, e1, e2, e3, agg);
            gemm_relu_kernel<<<NN / 32, 256, 0, stream>>>(
                x, agg, W1 + l * HID * HID, b1 + l * HID, agg);
            gemm_ln_res_kernel<<<NN / 32, 256, 0, stream>>>(
                agg, W2 + l * HID * HID, b2 + l * HID,
                lg + l * HID, lb + l * HID, x);
        }
    }

    hipMemsetAsync(sums, 0,
                   (size_t)BB * HID * sizeof(float) + BB * sizeof(int), stream);
    {
        int waves = (NN + PCHUNK - 1) / PCHUNK;             // 3125
        int blocks = (waves + 3) / 4;                       // 4 waves/block
        pool_kernel<<<blocks, 256, 0, stream>>>(x, batch, sums, cnt);
    }
    head_kernel<<<BB, 128, 0, stream>>>(
        sums, cnt, pW1, pb1, pW2, pb2, pg, pbn, oW, ob, out);
}

// Round 8
// 1065.886 us; speedup vs baseline: 11.0370x; 1.2557x over previous
//
#include <hip/hip_runtime.h>

#define HID 128
#define NN  100000
#define EE  1600000
#define BB  512
#define LL  4

typedef __attribute__((ext_vector_type(8))) short bf16x8;
typedef __attribute__((ext_vector_type(4))) float f32x4;

__device__ __forceinline__ unsigned short f32_to_bf16(float f) {
    union { float f; unsigned u; } c; c.f = f;
    unsigned r = c.u + 0x7FFFu + ((c.u >> 16) & 1u);
    return (unsigned short)(r >> 16);
}
__device__ __forceinline__ float bf16_to_f32(unsigned short h) {
    union { unsigned u; float f; } c; c.u = ((unsigned)h) << 16; return c.f;
}

// ============================ CSR build ====================================
__global__ __launch_bounds__(256) void hist_kernel(
    const int* __restrict__ ei, int* __restrict__ R)
{
    int e = blockIdx.x * 256 + threadIdx.x;
    if (e >= EE) return;
    atomicAdd(&R[ei[EE + e] + 1], 1);
}

__global__ __launch_bounds__(256) void scan1_kernel(int* __restrict__ R,
                                                    int* __restrict__ aux, int n)
{
    __shared__ int sh[256];
    int base = blockIdx.x * 1024;
    int t = threadIdx.x;
    int v[4]; int s = 0;
#pragma unroll
    for (int i = 0; i < 4; ++i) {
        int idx = base + t * 4 + i;
        v[i] = (idx < n) ? R[idx] : 0;
        s += v[i];
    }
    sh[t] = s; __syncthreads();
#pragma unroll
    for (int off = 1; off < 256; off <<= 1) {
        int val = (t >= off) ? sh[t - off] : 0;
        __syncthreads();
        sh[t] += val;
        __syncthreads();
    }
    int run = (t == 0) ? 0 : sh[t - 1];
#pragma unroll
    for (int i = 0; i < 4; ++i) {
        int idx = base + t * 4 + i;
        run += v[i];
        if (idx < n) R[idx] = run;
    }
    if (t == 255) aux[blockIdx.x] = sh[255];
}

__global__ __launch_bounds__(128) void scan2_kernel(int* __restrict__ aux, int nb)
{
    __shared__ int sh[128];
    int t = threadIdx.x;
    sh[t] = (t < nb) ? aux[t] : 0;
    __syncthreads();
#pragma unroll
    for (int off = 1; off < 128; off <<= 1) {
        int val = (t >= off) ? sh[t - off] : 0;
        __syncthreads();
        sh[t] += val;
        __syncthreads();
    }
    if (t < nb) aux[t] = sh[t];
}

__global__ __launch_bounds__(256) void scan3_kernel(int* __restrict__ R,
                                                    const int* __restrict__ aux, int n)
{
    int b = blockIdx.x + 1;
    int add = aux[b - 1];
#pragma unroll
    for (int i = 0; i < 4; ++i) {
        int idx = b * 1024 + threadIdx.x * 4 + i;
        if (idx < n) R[idx] += add;
    }
}

// fill with PACKED records: src(17b) | a0(5b) | a1(5b) | a2(5b)
__global__ __launch_bounds__(256) void fill_kernel(
    const int* __restrict__ ei, const int* __restrict__ ea,
    int* __restrict__ R, unsigned int* __restrict__ csr)
{
    int e = blockIdx.x * 256 + threadIdx.x;
    if (e >= EE) return;
    int pos = atomicAdd(&R[ei[EE + e]], 1);
    unsigned int rec = (unsigned int)ei[e]
                     | ((unsigned int)ea[e * 3 + 0] << 17)
                     | ((unsigned int)ea[e * 3 + 1] << 22)
                     | ((unsigned int)ea[e * 3 + 2] << 27);
    csr[pos] = rec;
}

// ================= W prep: split f32 -> bf16 hi/lo, swizzle ================
// Dest per (layer,mat): [8 nb][4 kstep][64 lane][8 j] bf16, hi then lo block.
// lane = quad*16 + nl supplies B[k=kstep*32+quad*8+j][n=nb*16+nl].
__global__ __launch_bounds__(256) void wprep_kernel(
    const float* __restrict__ W1, const float* __restrict__ W2,
    unsigned short* __restrict__ wf)
{
    int t = blockIdx.x * 256 + threadIdx.x;
    if (t >= LL * 2 * 16384) return;
    int layer = t >> 15;
    int rem = t & 32767;
    int mat = rem >> 14;
    int idx = rem & 16383;
    int k = idx >> 7, n = idx & 127;
    const float* W = (mat ? W2 : W1) + layer * 16384;
    float w = W[k * 128 + n];
    unsigned short hi = f32_to_bf16(w);
    unsigned short lo = f32_to_bf16(w - bf16_to_f32(hi));
    int nb = n >> 4, nl = n & 15, kstep = k >> 5, quad = (k >> 3) & 3, j = k & 7;
    int di = ((nb * 4 + kstep) * 64 + (quad * 16 + nl)) * 8 + j;
    unsigned short* base = wf + (size_t)((layer * 2 + mat) * 2) * 16384;
    base[di] = hi;
    base[16384 + di] = lo;
}

// ============================ embedding ====================================
__global__ __launch_bounds__(256) void embed_kernel(
    const int* __restrict__ x_idx, const float* __restrict__ node_emb,
    float* __restrict__ x)
{
    int t = blockIdx.x * 256 + threadIdx.x;
    int node = t >> 5, j = t & 31;
    if (node >= NN) return;
    ((float4*)x)[node * 32 + j] =
        ((const float4*)node_emb)[x_idx[node] * 32 + j];
}

// ====================== gather aggregation (CSR) ===========================
__device__ __forceinline__ float4 edge_term(
    unsigned int rec, int l32, const float* __restrict__ x,
    const float* __restrict__ e1, const float* __restrict__ e2,
    const float* __restrict__ e3)
{
    int src = rec & 0x1FFFF;
    int i0 = (rec >> 17) & 31, i1 = (rec >> 22) & 31, i2 = (rec >> 27) & 31;
    float4 v  = ((const float4*)x )[src * 32 + l32];
    float4 w1 = ((const float4*)e1)[i0  * 32 + l32];
    float4 w2 = ((const float4*)e2)[i1  * 32 + l32];
    float4 w3 = ((const float4*)e3)[i2  * 32 + l32];
    float4 r;
    r.x = fmaxf(v.x + w1.x + w2.x + w3.x, 0.f);
    r.y = fmaxf(v.y + w1.y + w2.y + w3.y, 0.f);
    r.z = fmaxf(v.z + w1.z + w2.z + w3.z, 0.f);
    r.w = fmaxf(v.w + w1.w + w2.w + w3.w, 0.f);
    return r;
}

__global__ __launch_bounds__(256) void gather_kernel(
    const float* __restrict__ x,
    const float* __restrict__ e1, const float* __restrict__ e2,
    const float* __restrict__ e3,
    const int* __restrict__ rowend, const unsigned int* __restrict__ csr,
    float* __restrict__ agg)
{
    int wid  = (blockIdx.x * 256 + threadIdx.x) >> 6;
    int lane = threadIdx.x & 63;
    int half = lane >> 5;
    int l32  = lane & 31;
    if (wid >= NN) return;
    int beg = (wid == 0) ? 0 : rowend[wid - 1];
    int end = rowend[wid];

    float4 a0 = make_float4(0.f, 0.f, 0.f, 0.f);
    float4 a1 = make_float4(0.f, 0.f, 0.f, 0.f);
    float4 a2 = make_float4(0.f, 0.f, 0.f, 0.f);
    float4 a3 = make_float4(0.f, 0.f, 0.f, 0.f);
    int p = beg + half;
    for (; p + 6 < end; p += 8) {
        unsigned int r0 = csr[p];
        unsigned int r1 = csr[p + 2];
        unsigned int r2 = csr[p + 4];
        unsigned int r3 = csr[p + 6];
        float4 t0 = edge_term(r0, l32, x, e1, e2, e3);
        float4 t1 = edge_term(r1, l32, x, e1, e2, e3);
        float4 t2 = edge_term(r2, l32, x, e1, e2, e3);
        float4 t3 = edge_term(r3, l32, x, e1, e2, e3);
        a0.x += t0.x; a0.y += t0.y; a0.z += t0.z; a0.w += t0.w;
        a1.x += t1.x; a1.y += t1.y; a1.z += t1.z; a1.w += t1.w;
        a2.x += t2.x; a2.y += t2.y; a2.z += t2.z; a2.w += t2.w;
        a3.x += t3.x; a3.y += t3.y; a3.z += t3.z; a3.w += t3.w;
    }
    for (; p < end; p += 2) {
        float4 t0 = edge_term(csr[p], l32, x, e1, e2, e3);
        a0.x += t0.x; a0.y += t0.y; a0.z += t0.z; a0.w += t0.w;
    }
    float4 acc;
    acc.x = (a0.x + a1.x) + (a2.x + a3.x);
    acc.y = (a0.y + a1.y) + (a2.y + a3.y);
    acc.z = (a0.z + a1.z) + (a2.z + a3.z);
    acc.w = (a0.w + a1.w) + (a2.w + a3.w);
    acc.x += __shfl_xor(acc.x, 32);
    acc.y += __shfl_xor(acc.y, 32);
    acc.z += __shfl_xor(acc.z, 32);
    acc.w += __shfl_xor(acc.w, 32);
    if (half == 0)
        ((float4*)agg)[wid * 32 + l32] = acc;
}

// =================== fallback atomic edge scatter ==========================
__global__ __launch_bounds__(256) void edge_kernel(
    const float* __restrict__ x, const int* __restrict__ ei,
    const int* __restrict__ ea, const float* __restrict__ e1,
    const float* __restrict__ e2, const float* __restrict__ e3,
    float* __restrict__ agg)
{
    int t = blockIdx.x * 256 + threadIdx.x;
    int e = t >> 5, j = t & 31;
    if (e >= EE) return;
    int src = ei[e];
    int dst = ei[EE + e];
    int a0 = ea[e * 3 + 0], a1 = ea[e * 3 + 1], a2 = ea[e * 3 + 2];
    float4 v  = ((const float4*)x )[src * 32 + j];
    float4 w1 = ((const float4*)e1)[a0  * 32 + j];
    float4 w2 = ((const float4*)e2)[a1  * 32 + j];
    float4 w3 = ((const float4*)e3)[a2  * 32 + j];
    float mx = fmaxf(v.x + w1.x + w2.x + w3.x, 0.f);
    float my = fmaxf(v.y + w1.y + w2.y + w3.y, 0.f);
    float mz = fmaxf(v.z + w1.z + w2.z + w3.z, 0.f);
    float mw = fmaxf(v.w + w1.w + w2.w + w3.w, 0.f);
    float* ag = agg + (size_t)dst * HID + j * 4;
    atomicAdd(ag + 0, mx);
    atomicAdd(ag + 1, my);
    atomicAdd(ag + 2, mz);
    atomicAdd(ag + 3, mw);
}

// ==================== fused layer MLP via split-bf16 MFMA ==================
// h = x+agg (split hi/lo bf16); t = relu(h@W1+b1) (split); u = t@W2+b2;
// x += relu(LN(u)).  3 MFMAs (hi*hi, lo*hi, hi*lo) approximate f32 product.
// Tile 32 rows x 128 cols, 4 waves: wave = (rb = w&1) row-block x 4 col-blocks.
#define TPAD 136   // bf16 row stride (16B-aligned, breaks pow2)
#define UPAD 132   // f32 row stride for u

__global__ __launch_bounds__(256) void mlp_mfma_kernel(
    const float* __restrict__ xin, const float* __restrict__ agg,
    const unsigned short* __restrict__ wf,   // this layer: [mat][hi/lo][16384]
    const float* __restrict__ b1, const float* __restrict__ b2,
    const float* __restrict__ gamma, const float* __restrict__ beta,
    float* __restrict__ x)
{
    // region A: h_hi/h_lo (2 x 8704 B), later aliased by u (16896 B f32)
    __shared__ __align__(16) char smemA[17408];
    __shared__ __align__(16) unsigned short t_hi[32 * TPAD];
    __shared__ __align__(16) unsigned short t_lo[32 * TPAD];
    unsigned short* h_hi = (unsigned short*)smemA;
    unsigned short* h_lo = (unsigned short*)(smemA + 8704);
    float* u_s = (float*)smemA;

    int tid = threadIdx.x;
    int rbase = blockIdx.x * 32;

    // ---- stage h = x + agg, split into hi/lo bf16 ----
    for (int idx = tid; idx < 32 * 32; idx += 256) {
        int r = idx >> 5, c4 = idx & 31;
        float4 xv = ((const float4*)xin)[(rbase + r) * 32 + c4];
        float4 av = ((const float4*)agg)[(rbase + r) * 32 + c4];
        float h0 = xv.x + av.x, h1 = xv.y + av.y;
        float h2 = xv.z + av.z, h3 = xv.w + av.w;
        unsigned short i0 = f32_to_bf16(h0), i1 = f32_to_bf16(h1);
        unsigned short i2 = f32_to_bf16(h2), i3 = f32_to_bf16(h3);
        ushort4 vh = make_ushort4(i0, i1, i2, i3);
        ushort4 vl = make_ushort4(f32_to_bf16(h0 - bf16_to_f32(i0)),
                                  f32_to_bf16(h1 - bf16_to_f32(i1)),
                                  f32_to_bf16(h2 - bf16_to_f32(i2)),
                                  f32_to_bf16(h3 - bf16_to_f32(i3)));
        int o = r * TPAD + c4 * 4;
        *(ushort4*)&h_hi[o] = vh;
        *(ushort4*)&h_lo[o] = vl;
    }
    __syncthreads();

    int lane = tid & 63;
    int wave = tid >> 6;
    int rb   = wave & 1;           // row block (16 rows)
    int cbg  = (wave >> 1) * 4;    // first of 4 col blocks
    int quad = lane >> 4, nl = lane & 15;
    int arow = rb * 16 + nl;

    const unsigned short* w1_hi = wf;
    const unsigned short* w1_lo = wf + 16384;
    const unsigned short* w2_hi = wf + 32768;
    const unsigned short* w2_lo = wf + 49152;

    // ---- GEMM1: t = relu(h @ W1 + b1) ----
    {
        f32x4 acc[4] = {};
#pragma unroll
        for (int ks = 0; ks < 4; ++ks) {
            int koff = ks * 32 + quad * 8;
            bf16x8 a_hi = *(const bf16x8*)&h_hi[arow * TPAD + koff];
            bf16x8 a_lo = *(const bf16x8*)&h_lo[arow * TPAD + koff];
#pragma unroll
            for (int cb = 0; cb < 4; ++cb) {
                int off = (((cbg + cb) * 4 + ks) * 64 + lane) * 8;
                bf16x8 b_hi = *(const bf16x8*)&w1_hi[off];
                bf16x8 b_lo = *(const bf16x8*)&w1_lo[off];
                acc[cb] = __builtin_amdgcn_mfma_f32_16x16x32_bf16(a_hi, b_hi, acc[cb], 0, 0, 0);
                acc[cb] = __builtin_amdgcn_mfma_f32_16x16x32_bf16(a_lo, b_hi, acc[cb], 0, 0, 0);
                acc[cb] = __builtin_amdgcn_mfma_f32_16x16x32_bf16(a_hi, b_lo, acc[cb], 0, 0, 0);
            }
        }
#pragma unroll
        for (int cb = 0; cb < 4; ++cb) {
            int col = (cbg + cb) * 16 + nl;
            float bv = b1[col];
#pragma unroll
            for (int r = 0; r < 4; ++r) {
                int row = rb * 16 + quad * 4 + r;
                float v = fmaxf(acc[cb][r] + bv, 0.f);
                unsigned short hi = f32_to_bf16(v);
                t_hi[row * TPAD + col] = hi;
                t_lo[row * TPAD + col] = f32_to_bf16(v - bf16_to_f32(hi));
            }
        }
    }
    __syncthreads();   // all GEMM1 h-reads done; t complete

    // ---- GEMM2: u = t @ W2 + b2 (u overwrites h region) ----
    {
        f32x4 acc[4] = {};
#pragma unroll
        for (int ks = 0; ks < 4; ++ks) {
            int koff = ks * 32 + quad * 8;
            bf16x8 a_hi = *(const bf16x8*)&t_hi[arow * TPAD + koff];
            bf16x8 a_lo = *(const bf16x8*)&t_lo[arow * TPAD + koff];
#pragma unroll
            for (int cb = 0; cb < 4; ++cb) {
                int off = (((cbg + cb) * 4 + ks) * 64 + lane) * 8;
                bf16x8 b_hi = *(const bf16x8*)&w2_hi[off];
                bf16x8 b_lo = *(const bf16x8*)&w2_lo[off];
                acc[cb] = __builtin_amdgcn_mfma_f32_16x16x32_bf16(a_hi, b_hi, acc[cb], 0, 0, 0);
                acc[cb] = __builtin_amdgcn_mfma_f32_16x16x32_bf16(a_lo, b_hi, acc[cb], 0, 0, 0);
                acc[cb] = __builtin_amdgcn_mfma_f32_16x16x32_bf16(a_hi, b_lo, acc[cb], 0, 0, 0);
            }
        }
#pragma unroll
        for (int cb = 0; cb < 4; ++cb) {
            int col = (cbg + cb) * 16 + nl;
            float bv = b2[col];
#pragma unroll
            for (int r = 0; r < 4; ++r) {
                int row = rb * 16 + quad * 4 + r;
                u_s[row * UPAD + col] = acc[cb][r] + bv;
            }
        }
    }
    __syncthreads();

    // ---- LN + relu + residual ----
    {
        int tc = tid & 31, tr = tid >> 5;
        float4 gv  = ((const float4*)gamma)[tc];
        float4 btv = ((const float4*)beta )[tc];
#pragma unroll
        for (int j = 0; j < 4; ++j) {
            float4 u4 = *(const float4*)&u_s[(tr * 4 + j) * UPAD + tc * 4];
            float s = u4.x + u4.y + u4.z + u4.w;
            float q = u4.x*u4.x + u4.y*u4.y + u4.z*u4.z + u4.w*u4.w;
#pragma unroll
            for (int off = 1; off < 32; off <<= 1) {
                s += __shfl_xor(s, off, 64);
                q += __shfl_xor(q, off, 64);
            }
            float m   = s * (1.f / 128.f);
            float var = q * (1.f / 128.f) - m * m;
            float rs  = rsqrtf(var + 1e-5f);
            int r = rbase + tr * 4 + j;
            float4 xo = ((float4*)x)[r * 32 + tc];
            float4 o;
            o.x = xo.x + fmaxf((u4.x - m) * rs * gv.x + btv.x, 0.f);
            o.y = xo.y + fmaxf((u4.y - m) * rs * gv.y + btv.y, 0.f);
            o.z = xo.z + fmaxf((u4.z - m) * rs * gv.z + btv.z, 0.f);
            o.w = xo.w + fmaxf((u4.w - m) * rs * gv.w + btv.w, 0.f);
            ((float4*)x)[r * 32 + tc] = o;
        }
    }
}

// ============== fallback split GEMMs (non-fast path only) ==================
__global__ __launch_bounds__(256) void gemm_relu_kernel(
    const float* __restrict__ x, const float* __restrict__ agg,
    const float* __restrict__ W, const float* __restrict__ bias,
    float* __restrict__ t)
{
    __shared__ float h_s[32 * 129];
    int tid = threadIdx.x;
    int tc = tid & 31, tr = tid >> 5;
    int rbase = blockIdx.x * 32;
    for (int idx = tid; idx < 32 * 128; idx += 256) {
        int r = idx >> 7, k = idx & 127;
        int g = (rbase + r) * HID + k;
        h_s[r * 129 + k] = x[g] + agg[g];
    }
    __syncthreads();
    float acc[4][4] = {};
    const float4* W4 = (const float4*)W;
#pragma unroll 4
    for (int k = 0; k < 128; ++k) {
        float4 w = W4[k * 32 + tc];
#pragma unroll
        for (int j = 0; j < 4; ++j) {
            float hv = h_s[(tr * 4 + j) * 129 + k];
            acc[j][0] = fmaf(hv, w.x, acc[j][0]);
            acc[j][1] = fmaf(hv, w.y, acc[j][1]);
            acc[j][2] = fmaf(hv, w.z, acc[j][2]);
            acc[j][3] = fmaf(hv, w.w, acc[j][3]);
        }
    }
    float4 bv = ((const float4*)bias)[tc];
#pragma unroll
    for (int j = 0; j < 4; ++j) {
        int r = rbase + tr * 4 + j;
        float4 o;
        o.x = fmaxf(acc[j][0] + bv.x, 0.f);
        o.y = fmaxf(acc[j][1] + bv.y, 0.f);
        o.z = fmaxf(acc[j][2] + bv.z, 0.f);
        o.w = fmaxf(acc[j][3] + bv.w, 0.f);
        ((float4*)t)[r * 32 + tc] = o;
    }
}

__global__ __launch_bounds__(256) void gemm_ln_res_kernel(
    const float* __restrict__ t, const float* __restrict__ W,
    const float* __restrict__ bias, const float* __restrict__ gamma,
    const float* __restrict__ beta, float* __restrict__ x)
{
    __shared__ float h_s[32 * 129];
    int tid = threadIdx.x;
    int tc = tid & 31, tr = tid >> 5;
    int rbase = blockIdx.x * 32;
    for (int idx = tid; idx < 32 * 128; idx += 256) {
        int r = idx >> 7, k = idx & 127;
        h_s[r * 129 + k] = t[(rbase + r) * HID + k];
    }
    __syncthreads();
    float acc[4][4] = {};
    const float4* W4 = (const float4*)W;
#pragma unroll 4
    for (int k = 0; k < 128; ++k) {
        float4 w = W4[k * 32 + tc];
#pragma unroll
        for (int j = 0; j < 4; ++j) {
            float hv = h_s[(tr * 4 + j) * 129 + k];
            acc[j][0] = fmaf(hv, w.x, acc[j][0]);
            acc[j][1] = fmaf(hv, w.y, acc[j][1]);
            acc[j][2] = fmaf(hv, w.z, acc[j][2]);
            acc[j][3] = fmaf(hv, w.w, acc[j][3]);
        }
    }
    float4 bv  = ((const float4*)bias )[tc];
    float4 gv  = ((const float4*)gamma)[tc];
    float4 btv = ((const float4*)beta )[tc];
#pragma unroll
    for (int j = 0; j < 4; ++j) {
        acc[j][0] += bv.x; acc[j][1] += bv.y;
        acc[j][2] += bv.z; acc[j][3] += bv.w;
        float s = acc[j][0] + acc[j][1] + acc[j][2] + acc[j][3];
        float q = acc[j][0]*acc[j][0] + acc[j][1]*acc[j][1]
                + acc[j][2]*acc[j][2] + acc[j][3]*acc[j][3];
#pragma unroll
        for (int off = 1; off < 32; off <<= 1) {
            s += __shfl_xor(s, off, 64);
            q += __shfl_xor(q, off, 64);
        }
        float m   = s * (1.f / 128.f);
        float var = q * (1.f / 128.f) - m * m;
        float rs  = rsqrtf(var + 1e-5f);
        int r = rbase + tr * 4 + j;
        float4 xo = ((float4*)x)[r * 32 + tc];
        float4 o;
        o.x = xo.x + fmaxf((acc[j][0] - m) * rs * gv.x + btv.x, 0.f);
        o.y = xo.y + fmaxf((acc[j][1] - m) * rs * gv.y + btv.y, 0.f);
        o.z = xo.z + fmaxf((acc[j][2] - m) * rs * gv.z + btv.z, 0.f);
        o.w = xo.w + fmaxf((acc[j][3] - m) * rs * gv.w + btv.w, 0.f);
        ((float4*)x)[r * 32 + tc] = o;
    }
}

// ============================ mean pool ====================================
#define PCHUNK 32
__global__ __launch_bounds__(256) void pool_kernel(
    const float* __restrict__ x, const int* __restrict__ batch,
    float* __restrict__ sums, int* __restrict__ cnt)
{
    int wave = (blockIdx.x * 256 + threadIdx.x) >> 6;
    int lane = threadIdx.x & 63;
    int n0 = wave * PCHUNK;
    if (n0 >= NN) return;
    int n1 = n0 + PCHUNK; if (n1 > NN) n1 = NN;

    float2 acc = make_float2(0.f, 0.f);
    int cur = batch[n0];
    int run = 0;
    for (int n = n0; n < n1; ++n) {
        int b = batch[n];
        if (b != cur) {
            float* sp = sums + cur * HID + lane * 2;
            atomicAdd(sp + 0, acc.x);
            atomicAdd(sp + 1, acc.y);
            if (lane == 0) atomicAdd(&cnt[cur], run);
            acc = make_float2(0.f, 0.f);
            run = 0; cur = b;
        }
        float2 v = ((const float2*)x)[(size_t)n * 64 + lane];
        acc.x += v.x; acc.y += v.y; ++run;
    }
    float* sp = sums + cur * HID + lane * 2;
    atomicAdd(sp + 0, acc.x);
    atomicAdd(sp + 1, acc.y);
    if (lane == 0) atomicAdd(&cnt[cur], run);
}

// ============================ head =========================================
__global__ __launch_bounds__(128) void head_kernel(
    const float* __restrict__ sums, const int* __restrict__ cnt,
    const float* __restrict__ pW1, const float* __restrict__ pb1,
    const float* __restrict__ pW2, const float* __restrict__ pb2,
    const float* __restrict__ pg, const float* __restrict__ pbn,
    const float* __restrict__ oW, const float* __restrict__ ob,
    float* __restrict__ out)
{
    __shared__ float s0[128], s1[128], red[4];
    int b = blockIdx.x, c = threadIdx.x;

    float cn = fmaxf((float)cnt[b], 1.f);
    s0[c] = sums[b * HID + c] / cn;
    __syncthreads();

    float a = pb1[c];
#pragma unroll 4
    for (int k = 0; k < HID; ++k) a = fmaf(s0[k], pW1[k * HID + c], a);
    a = fmaxf(a, 0.f);
    s1[c] = a;
    __syncthreads();

    float u = pb2[c];
#pragma unroll 4
    for (int k = 0; k < HID; ++k) u = fmaf(s1[k], pW2[k * HID + c], u);

    float s = u, q = u * u;
#pragma unroll
    for (int off = 1; off < 64; off <<= 1) {
        s += __shfl_xor(s, off, 64);
        q += __shfl_xor(q, off, 64);
    }
    if ((c & 63) == 0) { red[(c >> 6) * 2] = s; red[(c >> 6) * 2 + 1] = q; }
    __syncthreads();
    float S = red[0] + red[2], Q = red[1] + red[3];
    float m = S * (1.f / 128.f);
    float var = Q * (1.f / 128.f) - m * m;
    float rs = rsqrtf(var + 1e-5f);
    float v = fmaxf((u - m) * rs * pg[c] + pbn[c], 0.f);

    float p = v * oW[c];
#pragma unroll
    for (int off = 1; off < 64; off <<= 1) p += __shfl_xor(p, off, 64);
    __syncthreads();
    if ((c & 63) == 0) red[c >> 6] = p;
    __syncthreads();
    if (c == 0) {
        float tot = red[0] + red[1] + ob[0];
        out[b] = 1.f / (1.f + expf(-tot));
    }
}

// ===========================================================================
extern "C" void kernel_launch(void* const* d_in, const int* in_sizes, int n_in,
                              void* d_out, int out_size, void* d_ws, size_t ws_size,
                              hipStream_t stream)
{
    const int*   x_idx    = (const int*)d_in[0];
    const int*   ei       = (const int*)d_in[1];
    const int*   ea       = (const int*)d_in[2];
    const int*   batch    = (const int*)d_in[3];
    const float* node_emb = (const float*)d_in[4];
    const float* e1       = (const float*)d_in[5];
    const float* e2       = (const float*)d_in[6];
    const float* e3       = (const float*)d_in[7];
    const float* W1       = (const float*)d_in[8];
    const float* b1       = (const float*)d_in[9];
    const float* W2       = (const float*)d_in[10];
    const float* b2       = (const float*)d_in[11];
    const float* lg       = (const float*)d_in[12];
    const float* lb       = (const float*)d_in[13];
    const float* pW1      = (const float*)d_in[14];
    const float* pb1      = (const float*)d_in[15];
    const float* pW2      = (const float*)d_in[16];
    const float* pb2      = (const float*)d_in[17];
    const float* pg       = (const float*)d_in[18];
    const float* pbn      = (const float*)d_in[19];
    const float* oW       = (const float*)d_in[20];
    const float* ob       = (const float*)d_in[21];
    float* out = (float*)d_out;

    char* base = (char*)d_ws;
    size_t Sx = (size_t)NN * HID * sizeof(float);           // 51.2 MB
    float* x    = (float*)(base);
    float* agg  = (float*)(base + Sx);                      // also t (fallback)
    float* sums = (float*)(base + 2 * Sx);
    int*   cnt  = (int*)  (base + 2 * Sx + BB * HID * 4);
    int*   R    = (int*)  (base + 2 * Sx + BB * HID * 4 + 2048);
    unsigned int* csr = (unsigned int*)((char*)R + 400016);
    int*   aux  = (int*)  ((char*)csr + (size_t)EE * 4);
    unsigned short* wf = (unsigned short*)((char*)aux + 512);
    size_t need = ((char*)wf + (size_t)LL * 2 * 2 * 16384 * 2) - base;

    bool fast = (ws_size >= need);

    embed_kernel<<<(NN * 32 + 255) / 256, 256, 0, stream>>>(x_idx, node_emb, x);

    if (fast) {
        const int n = NN + 1, NB = (n + 1023) / 1024;
        hipMemsetAsync(R, 0, (size_t)n * sizeof(int), stream);
        hist_kernel <<<(EE + 255) / 256, 256, 0, stream>>>(ei, R);
        scan1_kernel<<<NB, 256, 0, stream>>>(R, aux, n);
        scan2_kernel<<<1, 128, 0, stream>>>(aux, NB);
        scan3_kernel<<<NB - 1, 256, 0, stream>>>(R, aux, n);
        fill_kernel <<<(EE + 255) / 256, 256, 0, stream>>>(ei, ea, R, csr);
        wprep_kernel<<<(LL * 2 * 16384 + 255) / 256, 256, 0, stream>>>(W1, W2, wf);
    }

    for (int l = 0; l < LL; ++l) {
        if (fast) {
            gather_kernel<<<(NN * 64 + 255) / 256, 256, 0, stream>>>(
                x, e1, e2, e3, R, csr, agg);
            mlp_mfma_kernel<<<NN / 32, 256, 0, stream>>>(
                x, agg, wf + (size_t)l * 65536,
                b1 + l * HID, b2 + l * HID,
                lg + l * HID, lb + l * HID, x);
        } else {
            hipMemsetAsync(agg, 0, Sx, stream);
            edge_kernel<<<(EE * 32 + 255) / 256, 256, 0, stream>>>(
                x, ei, ea, e1, e2, e3, agg);
            gemm_relu_kernel<<<NN / 32, 256, 0, stream>>>(
                x, agg, W1 + l * HID * HID, b1 + l * HID, agg);
            gemm_ln_res_kernel<<<NN / 32, 256, 0, stream>>>(
                agg, W2 + l * HID * HID, b2 + l * HID,
                lg + l * HID, lb + l * HID, x);
        }
    }

    hipMemsetAsync(sums, 0,
                   (size_t)BB * HID * sizeof(float) + BB * sizeof(int), stream);
    {
        int waves = (NN + PCHUNK - 1) / PCHUNK;
        int blocks = (waves + 3) / 4;
        pool_kernel<<<blocks, 256, 0, stream>>>(x, batch, sums, cnt);
    }
    head_kernel<<<BB, 128, 0, stream>>>(
        sums, cnt, pW1, pb1, pW2, pb2, pg, pbn, oW, ob, out);
}